// Round 8
// baseline (1006.911 us; speedup 1.0000x reference)
//
#include <hip/hip_runtime.h>
#include <math.h>

typedef float  f32x4 __attribute__((ext_vector_type(4)));
typedef short  s16x8 __attribute__((ext_vector_type(8)));

__device__ __forceinline__ float b2f(ushort u) { return __uint_as_float(((unsigned)u) << 16); }
__device__ __forceinline__ ushort f2b(float f) {
    unsigned u = __float_as_uint(f);
    return (ushort)((u + 0x7FFFu + ((u >> 16) & 1u)) >> 16);
}
__device__ __forceinline__ void gload16(const void* g, void* l) {
    __builtin_amdgcn_global_load_lds((const __attribute__((address_space(1))) void*)g,
                                     (__attribute__((address_space(3))) void*)l, 16, 0, 0);
}

// ====== weight convert: fp32 OIHW -> bf16 hi/lo planes [CO][ksp*CI+ci] =====
__global__ __launch_bounds__(256)
void wcvt_kernel(const float* __restrict__ src, ushort* __restrict__ dsth,
                 ushort* __restrict__ dstl, int CI, int reorder, int total)
{
    int i = blockIdx.x * 256 + threadIdx.x;
    if (i >= total) return;
    float v;
    if (reorder) {
        int k9 = CI * 9;
        int co = i / k9; int rem = i - co * k9;
        int ksp = rem / CI; int ci = rem - ksp * CI;
        v = src[(size_t)(co * CI + ci) * 9 + ksp];
    } else {
        v = src[i];
    }
    ushort h = f2b(v);
    dsth[i] = h;
    dstl[i] = f2b(v - b2f(h));
}

// ================= split-bf16 MFMA implicit-GEMM ===========================
// A staged in LDS (2-buffer stage-ahead); B in REGISTERS, double-buffered
// across iterations (ping-pong sets, unroll-2) so B-load latency hides under
// the MFMA phase. LDS ~34.8KB -> 3+ blocks/CU. BM=128, BN=NB; 4 waves 2x2.
template<int KTOT, int CIN, int HH, int WW, int COUT, bool IM2COL, bool BIAS,
         bool STATS, int SPLITK, int NB>
__global__ __launch_bounds__(256, 3)
void gemm_kernel(const ushort* __restrict__ inH, const ushort* __restrict__ inL,
                 const ushort* __restrict__ wbh, const ushort* __restrict__ wbl,
                 const float* __restrict__ bias, float* __restrict__ out,
                 const ushort* __restrict__ zsrc0,
                 float* __restrict__ gsum, float* __restrict__ gsq)
{
    constexpr int ABUF = 16384;             // A: hi 8K | lo 8K per buffer
    constexpr int NI  = NB / 32;            // B frags per wave
    __shared__ union {
        char s[2 * ABUF];
        float c2[64][NB + 4];               // epilogue half-pass transpose
    } u;
    __shared__ float blkstat[NB][2];

    const int tid  = threadIdx.x;
    const int lane = tid & 63, wv = tid >> 6;
    const int lr = lane & 15, lg = lane >> 4;
    const int wm = wv >> 1,  wn = wv & 1;
    int gx = blockIdx.x;
    gx = (gx & 7) * (gridDim.x >> 3) + (gx >> 3);   // bijective XCD swizzle (grid.x % 8 == 0)
    const int m0 = gx * 128;
    const int n0 = blockIdx.y * NB;

    constexpr int NK  = KTOT / 32;
    constexpr int NKS = NK / SPLITK;
    const int kz = (SPLITK > 1) ? blockIdx.z : 0;
    const int kb = kz * NKS, ke = kb + NKS;
    float* obase = (SPLITK > 1)
        ? out + (size_t)kz * (size_t)gridDim.x * 128 * COUT : out;

    // ---- A staging precompute ----
    const int sch = tid & 3;
    int aco[2], apix[2], ay[2] = {0,0}, ax[2] = {0,0};
#pragma unroll
    for (int q = 0; q < 2; q++) {
        int row = (tid >> 2) + q * 64;
        aco[q] = ((sch ^ ((row >> 1) & 3)) << 3);
        int m = m0 + row;
        apix[q] = m;
        if constexpr (IM2COL) {
            int rem = m & (HH * WW - 1);
            ay[q] = rem / WW;
            ax[q] = rem & (WW - 1);
        }
    }

    // ---- B register-load pointers (16B contiguous per lane) ----
    const ushort* bph[NI];
    const ushort* bpl[NI];
#pragma unroll
    for (int ni = 0; ni < NI; ni++) {
        size_t off = (size_t)(n0 + wn * (NB / 2) + ni * 16 + lr) * KTOT + lg * 8;
        bph[ni] = wbh + off;
        bpl[ni] = wbl + off;
    }

    // ---- A fragment read offsets (conflict-free swizzle, verified r4) ----
    const int chunk_p = (lg ^ ((lr >> 1) & 3)) << 4;
    int afoff[4];
#pragma unroll
    for (int mi = 0; mi < 4; mi++) afoff[mi] = (wm * 64 + mi * 16 + lr) * 64 + chunk_p;

    float bv[NI];
#pragma unroll
    for (int ni = 0; ni < NI; ni++)
        bv[ni] = BIAS ? bias[n0 + wn * (NB / 2) + ni * 16 + lr] : 0.f;

    f32x4 acc[4][NI] = {};

    auto stageA = [&](int kt, int buf) {
        char* dA = u.s + buf * ABUF + wv * 1024;   // + q*4096; lane*16 added by HW
        if constexpr (IM2COL) {
            int ksp = (kt * 32) / CIN;
            int c0  = (kt * 32) & (CIN - 1);
            int d3  = ksp / 3;
            int dy = d3 - 1, dx = ksp - d3 * 3 - 1;
            int dpix = dy * WW + dx;
#pragma unroll
            for (int q = 0; q < 2; q++) {
                int iy = ay[q] + dy, ix = ax[q] + dx;
                bool ok = ((unsigned)iy < (unsigned)HH) && ((unsigned)ix < (unsigned)WW);
                size_t so = (size_t)(apix[q] + dpix) * CIN + c0 + aco[q];
                gload16(ok ? (const void*)(inH + so) : (const void*)(zsrc0 + aco[q]),
                        dA + q * 4096);
                gload16(ok ? (const void*)(inL + so) : (const void*)(zsrc0 + aco[q]),
                        dA + 8192 + q * 4096);
            }
        } else {
#pragma unroll
            for (int q = 0; q < 2; q++) {
                size_t so = (size_t)apix[q] * KTOT + kt * 32 + aco[q];
                gload16(inH + so, dA + q * 4096);
                gload16(inL + so, dA + 8192 + q * 4096);
            }
        }
    };
    auto loadB = [&](int kt, s16x8 (&bh)[NI], s16x8 (&bl)[NI]) {
#pragma unroll
        for (int ni = 0; ni < NI; ni++) {
            bh[ni] = *(const s16x8*)(bph[ni] + kt * 32);
            bl[ni] = *(const s16x8*)(bpl[ni] + kt * 32);
        }
    };
    auto computeK = [&](int buf, s16x8 (&bh)[NI], s16x8 (&bl)[NI]) {
        const char* base = u.s + buf * ABUF;
        s16x8 ah4[4], al4[4];
#pragma unroll
        for (int mi = 0; mi < 4; mi++) {
            ah4[mi] = *(const s16x8*)(base + afoff[mi]);
            al4[mi] = *(const s16x8*)(base + afoff[mi] + 8192);
        }
        __builtin_amdgcn_s_setprio(1);
#pragma unroll
        for (int mi = 0; mi < 4; mi++)
#pragma unroll
            for (int ni = 0; ni < NI; ni++) {
                acc[mi][ni] = __builtin_amdgcn_mfma_f32_16x16x32_bf16(
                    ah4[mi], bh[ni], acc[mi][ni], 0, 0, 0);
                acc[mi][ni] = __builtin_amdgcn_mfma_f32_16x16x32_bf16(
                    al4[mi], bh[ni], acc[mi][ni], 0, 0, 0);
                acc[mi][ni] = __builtin_amdgcn_mfma_f32_16x16x32_bf16(
                    ah4[mi], bl[ni], acc[mi][ni], 0, 0, 0);
            }
        __builtin_amdgcn_s_setprio(0);
    };

    s16x8 b0h[NI], b0l[NI], b1h[NI], b1l[NI];
    loadB(kb, b0h, b0l);
    stageA(kb, 0);
    __syncthreads();
    int cur = 0;
#pragma unroll 1
    for (int kt = kb; kt < ke; kt += 2) {
        // phase 0: compute kt (set0); prefetch kt+1 (A->LDS, B->set1)
        if (kt + 1 < ke) { stageA(kt + 1, cur ^ 1); loadB(kt + 1, b1h, b1l); }
        computeK(cur, b0h, b0l);
        __syncthreads();
        cur ^= 1;
        if (kt + 1 >= ke) break;
        // phase 1: compute kt+1 (set1); prefetch kt+2 (A->LDS, B->set0)
        if (kt + 2 < ke) { stageA(kt + 2, cur ^ 1); loadB(kt + 2, b0h, b0l); }
        computeK(cur, b1h, b1l);
        __syncthreads();
        cur ^= 1;
    }

    // ---- epilogue: bias, half-pass LDS transpose, fp32 store, BN stats ----
    if (STATS && tid < NB * 2) ((float*)blkstat)[tid] = 0.f;
    constexpr int NCH = NB / 8;        // 8-float chunks per row
    constexpr int RPI = 256 / NCH;     // rows per iteration
    constexpr int ITER = 64 / RPI;
    const int chunkE = tid & (NCH - 1), rbE = tid / NCH;
    float ss[8] = {0,0,0,0,0,0,0,0}, qq[8] = {0,0,0,0,0,0,0,0};
#pragma unroll
    for (int half = 0; half < 2; half++) {
        __syncthreads();
        if (wm == half) {
#pragma unroll
            for (int mi = 0; mi < 4; mi++)
#pragma unroll
                for (int ni = 0; ni < NI; ni++)
#pragma unroll
                    for (int r = 0; r < 4; r++)
                        u.c2[mi * 16 + lg * 4 + r][wn * (NB / 2) + ni * 16 + lr] =
                            acc[mi][ni][r] + bv[ni];
        }
        __syncthreads();
#pragma unroll
        for (int i = 0; i < ITER; i++) {
            int row = rbE + i * RPI;
            float v[8];
#pragma unroll
            for (int j = 0; j < 8; j++) {
                v[j] = u.c2[row][chunkE * 8 + j];
                if (STATS) { ss[j] += v[j]; qq[j] += v[j] * v[j]; }
            }
            size_t base = (size_t)(m0 + half * 64 + row) * COUT + n0 + chunkE * 8;
            *(float4*)&obase[base]     = make_float4(v[0], v[1], v[2], v[3]);
            *(float4*)&obase[base + 4] = make_float4(v[4], v[5], v[6], v[7]);
        }
    }
    if (STATS) {
#pragma unroll
        for (int j = 0; j < 8; j++) {
            atomicAdd(&blkstat[chunkE * 8 + j][0], ss[j]);
            atomicAdd(&blkstat[chunkE * 8 + j][1], qq[j]);
        }
        __syncthreads();
        if (tid < NB) {
            atomicAdd(&gsum[n0 + tid], blkstat[tid][0]);
            atomicAdd(&gsq[n0 + tid],  blkstat[tid][1]);
        }
    }
}

// ====== sum P split-K parts (+bias, +BN stats), COUT=256, 8 rows/block =====
template<int P, bool BIASF, bool STATSF>
__global__ __launch_bounds__(256)
void sumk_kernel(const float* __restrict__ parts, size_t pstride,
                 const float* __restrict__ bias, float* __restrict__ outp,
                 float* __restrict__ gsum, float* __restrict__ gsq)
{
    __shared__ float bst[256][2];
    int tid = threadIdx.x;
    if (STATSF) { bst[tid][0] = 0.f; bst[tid][1] = 0.f; __syncthreads(); }
    size_t row = (size_t)blockIdx.x * 8 + (tid >> 5);
    int c0 = (tid & 31) * 8;
    size_t base = row * 256 + c0;
    float v[8];
    float4 a0 = *(const float4*)&parts[base];
    float4 a1 = *(const float4*)&parts[base + 4];
    v[0] = a0.x; v[1] = a0.y; v[2] = a0.z; v[3] = a0.w;
    v[4] = a1.x; v[5] = a1.y; v[6] = a1.z; v[7] = a1.w;
#pragma unroll
    for (int p = 1; p < P; p++) {
        float4 b0 = *(const float4*)&parts[p * pstride + base];
        float4 b1 = *(const float4*)&parts[p * pstride + base + 4];
        v[0] += b0.x; v[1] += b0.y; v[2] += b0.z; v[3] += b0.w;
        v[4] += b1.x; v[5] += b1.y; v[6] += b1.z; v[7] += b1.w;
    }
    if (BIASF) {
#pragma unroll
        for (int j = 0; j < 8; j++) v[j] += bias[c0 + j];
    }
    *(float4*)&outp[base]     = make_float4(v[0], v[1], v[2], v[3]);
    *(float4*)&outp[base + 4] = make_float4(v[4], v[5], v[6], v[7]);
    if (STATSF) {
#pragma unroll
        for (int j = 0; j < 8; j++) {
            atomicAdd(&bst[c0 + j][0], v[j]);
            atomicAdd(&bst[c0 + j][1], v[j] * v[j]);
        }
        __syncthreads();
        atomicAdd(&gsum[tid], bst[tid][0]);
        atomicAdd(&gsq[tid],  bst[tid][1]);
    }
}

// ================= BN finalize: A=g*rsqrt(var+eps), B=b-mu*A ===============
__global__ void bn_finalize(const float* __restrict__ sum, const float* __restrict__ sq,
                            const float* __restrict__ g, const float* __restrict__ b,
                            float* __restrict__ A, float* __restrict__ Bc,
                            int C, float invN)
{
    int c = threadIdx.x;
    if (c < C) {
        float mu  = sum[c] * invN;
        float var = sq[c] * invN - mu * mu;
        float s   = rsqrtf(var + 1e-5f) * g[c];
        A[c]  = s;
        Bc[c] = b[c] - mu * s;
    }
}

// ==== BN affine + relu + 2x2 maxpool (fp32 NHWC in -> hi/lo bf16 planes) ===
template<int CC, int HH, int WW>
__global__ __launch_bounds__(256)
void bnpool_kernel(const float* __restrict__ in, const float* __restrict__ A,
                   const float* __restrict__ Bc, ushort* __restrict__ outH,
                   ushort* __restrict__ outL)
{
    constexpr int CH = CC / 8, PW = WW / 2, PH = HH / 2;
    int i = blockIdx.x * 256 + threadIdx.x;
    int cc = i & (CH - 1);
    int t2 = i / CH;
    int px = t2 & (PW - 1);
    int t3 = t2 / PW;
    int py = t3 & (PH - 1);
    int b  = t3 / PH;
    const float* p = in + (size_t)((b * HH + 2 * py) * WW + 2 * px) * CC + cc * 8;
    float v00[8], v01[8], v10[8], v11[8];
#pragma unroll
    for (int j = 0; j < 8; j++) {
        v00[j] = p[j];
        v01[j] = p[CC + j];
        v10[j] = p[(size_t)WW * CC + j];
        v11[j] = p[(size_t)WW * CC + CC + j];
    }
    unsigned pwh[4], pwl[4];
#pragma unroll
    for (int jj = 0; jj < 4; jj++) {
        ushort h2[2], l2[2];
#pragma unroll
        for (int k = 0; k < 2; k++) {
            int j = jj * 2 + k;
            int c = cc * 8 + j;
            float Av = A[c], Bv = Bc[c];
            float m = fmaxf(fmaxf(fmaf(v00[j], Av, Bv), fmaf(v01[j], Av, Bv)),
                            fmaxf(fmaf(v10[j], Av, Bv), fmaf(v11[j], Av, Bv)));
            m = fmaxf(m, 0.f);
            h2[k] = f2b(m);
            l2[k] = f2b(m - b2f(h2[k]));
        }
        pwh[jj] = (unsigned)h2[0] | ((unsigned)h2[1] << 16);
        pwl[jj] = (unsigned)l2[0] | ((unsigned)l2[1] << 16);
    }
    *(uint4*)&outH[(size_t)i * 8] = make_uint4(pwh[0], pwh[1], pwh[2], pwh[3]);
    *(uint4*)&outL[(size_t)i * 8] = make_uint4(pwl[0], pwl[1], pwl[2], pwl[3]);
}

// ======== conv1 (1->64, 64x64, fp32): MODE1 stats / MODE2 pool->planes =====
template<int MODE>
__global__ __launch_bounds__(256)
void conv1_kernel(const float* __restrict__ in, const float* __restrict__ wgt,
                  const float* __restrict__ bias, ushort* __restrict__ outH,
                  ushort* __restrict__ outL,
                  float* __restrict__ ssum, float* __restrict__ ssq,
                  const float* __restrict__ bnA, const float* __restrict__ bnB)
{
    __shared__ float slab[34][34];
    __shared__ float redbuf[4 * 8 * 2];
    const int tid = threadIdx.x;
    const int bg = blockIdx.x >> 2, tile = blockIdx.x & 3;
    const int ty = (tile >> 1) * 32, tx = (tile & 1) * 32;
    const int cout0 = blockIdx.y * 8;
    const int qy = tid >> 4, qx = tid & 15;
    const int oy = ty + 2 * qy, ox = tx + 2 * qx;

    for (int idx = tid; idx < 34 * 34; idx += 256) {
        int sy = idx / 34, sx = idx - sy * 34;
        int gy = ty + sy - 1, gx = tx + sx - 1;
        float v = 0.f;
        if (gy >= 0 && gy < 64 && gx >= 0 && gx < 64)
            v = in[((size_t)bg * 64 + gy) * 64 + gx];
        (&slab[0][0])[idx] = v;
    }
    __syncthreads();
    float v[4][4];
#pragma unroll
    for (int r = 0; r < 4; r++) {
        float2 a = *(const float2*)&slab[2 * qy + r][2 * qx];
        float2 b = *(const float2*)&slab[2 * qy + r][2 * qx + 2];
        v[r][0] = a.x; v[r][1] = a.y; v[r][2] = b.x; v[r][3] = b.y;
    }
    float acc[4][8];
#pragma unroll
    for (int oc = 0; oc < 8; oc++) {
        const float* w9 = wgt + (size_t)(cout0 + oc) * 9;
        float w0 = w9[0], w1 = w9[1], w2 = w9[2], w3 = w9[3], w4 = w9[4],
              w5 = w9[5], w6 = w9[6], w7 = w9[7], w8 = w9[8];
        float bs = bias[cout0 + oc];
#pragma unroll
        for (int dy = 0; dy < 2; dy++)
#pragma unroll
            for (int dx = 0; dx < 2; dx++) {
                float s = bs;
                s = fmaf(w0, v[dy][dx], s);
                s = fmaf(w1, v[dy][dx + 1], s);
                s = fmaf(w2, v[dy][dx + 2], s);
                s = fmaf(w3, v[dy + 1][dx], s);
                s = fmaf(w4, v[dy + 1][dx + 1], s);
                s = fmaf(w5, v[dy + 1][dx + 2], s);
                s = fmaf(w6, v[dy + 2][dx], s);
                s = fmaf(w7, v[dy + 2][dx + 1], s);
                s = fmaf(w8, v[dy + 2][dx + 2], s);
                acc[dy * 2 + dx][oc] = s;
            }
    }
    if constexpr (MODE == 1) {
        int wave = tid >> 6, lanei = tid & 63;
#pragma unroll
        for (int oc = 0; oc < 8; oc++) {
            float s  = acc[0][oc] + acc[1][oc] + acc[2][oc] + acc[3][oc];
            float q2 = acc[0][oc] * acc[0][oc] + acc[1][oc] * acc[1][oc] +
                       acc[2][oc] * acc[2][oc] + acc[3][oc] * acc[3][oc];
#pragma unroll
            for (int off = 32; off > 0; off >>= 1) {
                s  += __shfl_down(s, off);
                q2 += __shfl_down(q2, off);
            }
            if (lanei == 0) {
                redbuf[(wave * 8 + oc) * 2 + 0] = s;
                redbuf[(wave * 8 + oc) * 2 + 1] = q2;
            }
        }
        __syncthreads();
        if (tid < 8) {
            float s = 0.f, q2 = 0.f;
#pragma unroll
            for (int w = 0; w < 4; w++) {
                s  += redbuf[(w * 8 + tid) * 2 + 0];
                q2 += redbuf[(w * 8 + tid) * 2 + 1];
            }
            atomicAdd(&ssum[cout0 + tid], s);
            atomicAdd(&ssq[cout0 + tid], q2);
        }
    }
    if constexpr (MODE == 2) {
        unsigned pwh[4], pwl[4];
#pragma unroll
        for (int jj = 0; jj < 4; jj++) {
            ushort h2[2], l2[2];
#pragma unroll
            for (int k = 0; k < 2; k++) {
                int oc = jj * 2 + k;
                float Av = bnA[cout0 + oc], Bv = bnB[cout0 + oc];
                float m0_ = fmaxf(fmaf(acc[0][oc], Av, Bv), fmaf(acc[1][oc], Av, Bv));
                float m1_ = fmaxf(fmaf(acc[2][oc], Av, Bv), fmaf(acc[3][oc], Av, Bv));
                float m = fmaxf(fmaxf(m0_, m1_), 0.f);
                h2[k] = f2b(m);
                l2[k] = f2b(m - b2f(h2[k]));
            }
            pwh[jj] = (unsigned)h2[0] | ((unsigned)h2[1] << 16);
            pwl[jj] = (unsigned)l2[0] | ((unsigned)l2[1] << 16);
        }
        size_t base = (size_t)((bg * 32 + (oy >> 1)) * 32 + (ox >> 1)) * 64 + cout0;
        *(uint4*)&outH[base] = make_uint4(pwh[0], pwh[1], pwh[2], pwh[3]);
        *(uint4*)&outL[base] = make_uint4(pwl[0], pwl[1], pwl[2], pwl[3]);
    }
}

// =============== offset conv: 256 -> 18 channels at 4x4 (fp32) =============
__global__ __launch_bounds__(256)
void offconv_kernel(const ushort* __restrict__ hH, const ushort* __restrict__ hL,
                    const float* __restrict__ ow, const float* __restrict__ ob,
                    float* __restrict__ off)
{
    __shared__ float plane[256][36];
    int b = blockIdx.x, tid = threadIdx.x;
    for (int i = tid; i < 256 * 36; i += 256) (&plane[0][0])[i] = 0.f;
    __syncthreads();
    for (int i = tid; i < 4096; i += 256) {
        int px = i >> 8, c = i & 255;
        size_t idx = ((size_t)b * 16 + px) * 256 + c;
        plane[c][((px >> 2) + 1) * 6 + (px & 3) + 1] = b2f(hH[idx]) + b2f(hL[idx]);
    }
    __syncthreads();
    for (int o = tid; o < 288; o += 256) {
        int co = o >> 4, px = o & 15, y = px >> 2, x = px & 3;
        float s = ob[co];
        const float* wb = ow + (size_t)co * 256 * 9;
        for (int c = 0; c < 256; c++) {
            const float* wc = wb + c * 9;
            const float* pl = &plane[c][y * 6 + x];
#pragma unroll
            for (int r = 0; r < 3; r++)
#pragma unroll
                for (int k = 0; k < 3; k++)
                    s = fmaf(wc[r * 3 + k], pl[r * 6 + k], s);
        }
        off[((size_t)b * 18 + co) * 16 + px] = s;
    }
}

// ====== deformable sampling -> xo hi/lo bf16 planes [2048][2304] ===========
__global__ __launch_bounds__(256)
void sample_kernel(const ushort* __restrict__ hH, const ushort* __restrict__ hL,
                   const float* __restrict__ off, ushort* __restrict__ xoH,
                   ushort* __restrict__ xoL)
{
    __shared__ float plane[256][36];
    __shared__ int   tidx[144][4];
    __shared__ float twt[144][4];
    int b = blockIdx.x, tid = threadIdx.x;
    for (int i = tid; i < 256 * 36; i += 256) (&plane[0][0])[i] = 0.f;
    __syncthreads();
    for (int i = tid; i < 4096; i += 256) {
        int px = i >> 8, c = i & 255;
        size_t idx = ((size_t)b * 16 + px) * 256 + c;
        plane[c][((px >> 2) + 1) * 6 + (px & 3) + 1] = b2f(hH[idx]) + b2f(hL[idx]);
    }
    if (tid < 144) {
        int px = tid / 9, n = tid % 9;
        int y = px >> 2, x = px & 3;
        float ox_ = off[((size_t)b * 18 + 2 * n) * 16 + px];
        float oy_ = off[((size_t)b * 18 + 2 * n + 1) * 16 + px];
        float pxc = (float)(y + 1) + (float)(n / 3 - 1) + ox_;
        float pyc = (float)(x + 1) + (float)(n % 3 - 1) + oy_;
        if (pxc < 1.f || pxc > 4.f) pxc = floorf(pxc);
        if (pyc < 1.f || pyc > 4.f) pyc = floorf(pyc);
        pxc = fminf(fmaxf(pxc, 0.f), 5.f);
        pyc = fminf(fmaxf(pyc, 0.f), 5.f);
        float fx = floorf(pxc), fy = floorf(pyc);
        float qrbx = fminf(fx + 1.f, 5.f), qrby = fminf(fy + 1.f, 5.f);
        float wx_lt = 1.f + (fx - pxc), wx_rb = 1.f - (qrbx - pxc);
        float wy_lt = 1.f + (fy - pyc), wy_rb = 1.f - (qrby - pyc);
        tidx[tid][0] = (int)(fx * 6.f + fy);     twt[tid][0] = wx_lt * wy_lt;
        tidx[tid][1] = (int)(qrbx * 6.f + qrby); twt[tid][1] = wx_rb * wy_rb;
        tidx[tid][2] = (int)(fx * 6.f + qrby);   twt[tid][2] = wx_lt * wy_rb;
        tidx[tid][3] = (int)(qrbx * 6.f + fy);   twt[tid][3] = wx_rb * wy_lt;
    }
    __syncthreads();
    for (int s = tid; s < 36864; s += 256) {
        int px = s / 2304, k = s - px * 2304;
        int c = k / 9, n = k - c * 9;
        int t = px * 9 + n;
        const float* pc = plane[c];
        float v = twt[t][0] * pc[tidx[t][0]] + twt[t][1] * pc[tidx[t][1]] +
                  twt[t][2] * pc[tidx[t][2]] + twt[t][3] * pc[tidx[t][3]];
        ushort h = f2b(v);
        size_t o = ((size_t)b * 16 + px) * 2304 + k;
        xoH[o] = h;
        xoL[o] = f2b(v - b2f(h));
    }
}

// ============== bn5 stats over relu(dout fp32) =============================
__global__ __launch_bounds__(256)
void stats5_kernel(const float* __restrict__ dout, float* __restrict__ sum5,
                   float* __restrict__ sq5)
{
    __shared__ float rs[256], rq[256];
    int c = blockIdx.x, tid = threadIdx.x;
    float s = 0.f, q = 0.f;
    for (int i = tid; i < 2048; i += 256) {
        float v = fmaxf(dout[(size_t)i * 256 + c], 0.f);
        s += v; q += v * v;
    }
    rs[tid] = s; rq[tid] = q; __syncthreads();
    for (int st = 128; st > 0; st >>= 1) {
        if (tid < st) { rs[tid] += rs[tid + st]; rq[tid] += rq[tid + st]; }
        __syncthreads();
    }
    if (tid == 0) { sum5[c] = rs[0]; sq5[c] = rq[0]; }
}

// ====== head: relu -> bn5 folded into mean -> fc -> log_softmax ============
__global__ __launch_bounds__(256)
void final_kernel(const float* __restrict__ dout, const float* __restrict__ A5,
                  const float* __restrict__ B5, const float* __restrict__ fcw,
                  const float* __restrict__ fcb, float* __restrict__ out)
{
    __shared__ float hbar[256];
    __shared__ float red[256];
    int b = blockIdx.x, tid = threadIdx.x;
    float s = 0.f;
#pragma unroll 4
    for (int px = 0; px < 16; px++)
        s += fmaxf(dout[((size_t)b * 16 + px) * 256 + tid], 0.f);
    hbar[tid] = fmaf(A5[tid], s * (1.f / 16.f), B5[tid]);
    __syncthreads();
    float logit = -1e30f;
    if (tid < 250) {
        float acc = fcb[tid];
        const float4* wr = (const float4*)(fcw + (size_t)tid * 256);
        const float4* hv = (const float4*)hbar;
#pragma unroll 4
        for (int i = 0; i < 64; i++) {
            float4 w4 = wr[i], h4 = hv[i];
            acc = fmaf(w4.x, h4.x, acc); acc = fmaf(w4.y, h4.y, acc);
            acc = fmaf(w4.z, h4.z, acc); acc = fmaf(w4.w, h4.w, acc);
        }
        logit = acc;
    }
    red[tid] = logit; __syncthreads();
    for (int st = 128; st > 0; st >>= 1) {
        if (tid < st) red[tid] = fmaxf(red[tid], red[tid + st]);
        __syncthreads();
    }
    float mx = red[0]; __syncthreads();
    float e = (tid < 250) ? expf(logit - mx) : 0.f;
    red[tid] = e; __syncthreads();
    for (int st = 128; st > 0; st >>= 1) {
        if (tid < st) red[tid] += red[tid + st];
        __syncthreads();
    }
    float lse = logf(red[0]) + mx;
    if (tid < 250) out[(size_t)b * 250 + tid] = logit - lse;
}

// ===========================================================================
extern "C" void kernel_launch(void* const* d_in, const int* in_sizes, int n_in,
                              void* d_out, int out_size, void* d_ws, size_t ws_size,
                              hipStream_t stream)
{
    const float* s_in = (const float*)d_in[0];
    const float* c1w = (const float*)d_in[1];  const float* c1b = (const float*)d_in[2];
    const float* g1  = (const float*)d_in[3];  const float* b1  = (const float*)d_in[4];
    const float* c2w = (const float*)d_in[5];  const float* c2b = (const float*)d_in[6];
    const float* g2  = (const float*)d_in[7];  const float* b2  = (const float*)d_in[8];
    const float* c3w = (const float*)d_in[9];  const float* c3b = (const float*)d_in[10];
    const float* g3  = (const float*)d_in[11]; const float* b3  = (const float*)d_in[12];
    const float* c4w = (const float*)d_in[13]; const float* c4b = (const float*)d_in[14];
    const float* g4  = (const float*)d_in[15]; const float* b4  = (const float*)d_in[16];
    const float* ofw = (const float*)d_in[17]; const float* ofb = (const float*)d_in[18];
    const float* dcw = (const float*)d_in[19];
    const float* g5  = (const float*)d_in[20]; const float* b5  = (const float*)d_in[21];
    const float* fcw = (const float*)d_in[22]; const float* fcb = (const float*)d_in[23];

    float* ws   = (float*)d_ws;
    float* stat = ws;                       // 2560
    float* ab   = ws + 2560;                // 2560
    float* zpad = ws + 5120;                // 64
    ushort* w2h = (ushort*)(ws + 5184);
    ushort* w2l = (ushort*)(ws + 42048);
    ushort* w3h = (ushort*)(ws + 78912);
    ushort* w3l = (ushort*)(ws + 226368);
    ushort* w4h = (ushort*)(ws + 373824);
    ushort* w4l = (ushort*)(ws + 668736);
    ushort* wdh = (ushort*)(ws + 963648);
    ushort* wdl = (ushort*)(ws + 1258560);
    ushort* poolH = (ushort*)(ws + 1553472);   // 8,388,608 u max
    ushort* poolL = (ushort*)(ws + 5747776);
    float*  conv32 = ws + 9942080;             // conv2/conv3 outs (16.7M f max)
    float*  c4parts = ws + 9942080;            // conv4 split-K parts (4 x 2,097,152)
    float*  c4out   = ws + 18330688;           // conv4 summed (2,097,152)
    float*  dparts  = ws + 20427840;           // dconv split-K parts (8 x 524,288)
    ushort* xoH  = (ushort*)(ws + 9942080);    // 4,718,592 u (after conv4 parts dead)
    ushort* xoL  = (ushort*)(ws + 12301376);
    float*  dout = ws + 14660672;              // 524,288 f
    float*  offb = ws + 15184960;              // 36,864 f

    hipMemsetAsync(stat, 0, 2048 * sizeof(float), stream);
    hipMemsetAsync(zpad, 0, 256, stream);

    // weight split-conversions
    wcvt_kernel<<<(128 * 64 * 9 + 255) / 256, 256, 0, stream>>>(c2w, w2h, w2l, 64, 1, 128 * 64 * 9);
    wcvt_kernel<<<(256 * 128 * 9 + 255) / 256, 256, 0, stream>>>(c3w, w3h, w3l, 128, 1, 256 * 128 * 9);
    wcvt_kernel<<<(256 * 256 * 9 + 255) / 256, 256, 0, stream>>>(c4w, w4h, w4l, 256, 1, 256 * 256 * 9);
    wcvt_kernel<<<(256 * 2304 + 255) / 256, 256, 0, stream>>>(dcw, wdh, wdl, 256, 0, 256 * 2304);

    // ---- stage 1: conv1 (recompute trick) -> hi/lo NHWC [B,32,32,64] ----
    conv1_kernel<1><<<dim3(512, 8), 256, 0, stream>>>(s_in, c1w, c1b, nullptr, nullptr,
                                                      stat, stat + 256, nullptr, nullptr);
    bn_finalize<<<1, 256, 0, stream>>>(stat, stat + 256, g1, b1, ab, ab + 256, 64,
                                       1.0f / (128.f * 64.f * 64.f));
    conv1_kernel<2><<<dim3(512, 8), 256, 0, stream>>>(s_in, c1w, c1b, poolH, poolL,
                                                      nullptr, nullptr, ab, ab + 256);

    // ---- stage 2: conv2 GEMM (M=131072, N=128, K=576), BN=128 ----
    gemm_kernel<576, 64, 32, 32, 128, true, true, true, 1, 128>
        <<<dim3(1024, 1), 256, 0, stream>>>(
        poolH, poolL, w2h, w2l, c2b, conv32, (const ushort*)zpad, stat + 512, stat + 768);
    bn_finalize<<<1, 256, 0, stream>>>(stat + 512, stat + 768, g2, b2, ab + 512, ab + 768,
                                       128, 1.0f / (128.f * 32.f * 32.f));
    bnpool_kernel<128, 32, 32><<<2048, 256, 0, stream>>>(conv32, ab + 512, ab + 768, poolH, poolL);

    // ---- stage 3: conv3 GEMM (M=32768, N=256, K=1152), BN=128 ----
    gemm_kernel<1152, 128, 16, 16, 256, true, true, true, 1, 128>
        <<<dim3(256, 2), 256, 0, stream>>>(
        poolH, poolL, w3h, w3l, c3b, conv32, (const ushort*)zpad, stat + 1024, stat + 1280);
    bn_finalize<<<1, 256, 0, stream>>>(stat + 1024, stat + 1280, g3, b3, ab + 1024, ab + 1280,
                                       256, 1.0f / (128.f * 16.f * 16.f));
    bnpool_kernel<256, 16, 16><<<1024, 256, 0, stream>>>(conv32, ab + 1024, ab + 1280, poolH, poolL);

    // ---- stage 4: conv4 GEMM (M=8192, N=256, K=2304), BN=128, split-K=4 ----
    gemm_kernel<2304, 256, 8, 8, 256, true, false, false, 4, 128>
        <<<dim3(64, 2, 4), 256, 0, stream>>>(
        poolH, poolL, w4h, w4l, nullptr, c4parts, (const ushort*)zpad, nullptr, nullptr);
    sumk_kernel<4, true, true><<<1024, 256, 0, stream>>>(
        c4parts, 2097152, c4b, c4out, stat + 1536, stat + 1792);
    bn_finalize<<<1, 256, 0, stream>>>(stat + 1536, stat + 1792, g4, b4, ab + 1536, ab + 1792,
                                       256, 1.0f / (128.f * 8.f * 8.f));
    bnpool_kernel<256, 8, 8><<<256, 256, 0, stream>>>(c4out, ab + 1536, ab + 1792, poolH, poolL);

    // ---- deformable conv (split-K=8, odd NKS handled by tail break) ----
    offconv_kernel<<<128, 256, 0, stream>>>(poolH, poolL, ofw, ofb, offb);
    sample_kernel<<<128, 256, 0, stream>>>(poolH, poolL, offb, xoH, xoL);
    gemm_kernel<2304, 2304, 1, 1, 256, false, false, false, 8, 64>
        <<<dim3(16, 4, 8), 256, 0, stream>>>(
        xoH, xoL, wdh, wdl, nullptr, dparts, (const ushort*)zpad, nullptr, nullptr);
    sumk_kernel<8, false, false><<<256, 256, 0, stream>>>(
        dparts, 524288, nullptr, dout, nullptr, nullptr);

    // ---- bn5 + head ----
    stats5_kernel<<<256, 256, 0, stream>>>(dout, stat + 2048, stat + 2304);
    bn_finalize<<<1, 256, 0, stream>>>(stat + 2048, stat + 2304, g5, b5, ab + 2048, ab + 2304,
                                       256, 1.0f / 2048.f);
    final_kernel<<<128, 256, 0, stream>>>(dout, ab + 2048, ab + 2304, fcw, fcb, (float*)d_out);
}

// Round 9
// 454.537 us; speedup vs baseline: 2.2152x; 2.2152x over previous
//
#include <hip/hip_runtime.h>
#include <math.h>

typedef float  f32x4 __attribute__((ext_vector_type(4)));
typedef short  s16x8 __attribute__((ext_vector_type(8)));

__device__ __forceinline__ float b2f(ushort u) { return __uint_as_float(((unsigned)u) << 16); }
__device__ __forceinline__ ushort f2b(float f) {
    unsigned u = __float_as_uint(f);
    return (ushort)((u + 0x7FFFu + ((u >> 16) & 1u)) >> 16);
}
__device__ __forceinline__ void gload16(const void* g, void* l) {
    __builtin_amdgcn_global_load_lds((const __attribute__((address_space(1))) void*)g,
                                     (__attribute__((address_space(3))) void*)l, 16, 0, 0);
}

// ====== weight convert: fp32 OIHW -> bf16 hi/lo planes [CO][ksp*CI+ci] =====
__global__ __launch_bounds__(256)
void wcvt_kernel(const float* __restrict__ src, ushort* __restrict__ dsth,
                 ushort* __restrict__ dstl, int CI, int reorder, int total)
{
    int i = blockIdx.x * 256 + threadIdx.x;
    if (i >= total) return;
    float v;
    if (reorder) {
        int k9 = CI * 9;
        int co = i / k9; int rem = i - co * k9;
        int ksp = rem / CI; int ci = rem - ksp * CI;
        v = src[(size_t)(co * CI + ci) * 9 + ksp];
    } else {
        v = src[i];
    }
    ushort h = f2b(v);
    dsth[i] = h;
    dstl[i] = f2b(v - b2f(h));
}

// ================= split-bf16 MFMA implicit-GEMM (r6 core) =================
// 2-buffer stage-ahead, A+B staged in LDS via global_load_lds. BM=128, BN=NB;
// 4 waves 2x2, wave tile 64 x NB/2. acc += ah*wh + al*wh + ah*wl.
// FUSE: epilogue computes 2x2 maxpool of the pre-BN values and writes the
// pooled 1/4-size tensor (valid since BN affine A>0 -> pool/affine commute).
// BN stats are still accumulated over ALL pre-pool values.
template<int KTOT, int CIN, int HH, int WW, int COUT, bool IM2COL, bool BIAS,
         bool STATS, int SPLITK, int NB, bool FUSE>
__global__ __launch_bounds__(256)
void gemm_kernel(const ushort* __restrict__ inH, const ushort* __restrict__ inL,
                 const ushort* __restrict__ wbh, const ushort* __restrict__ wbl,
                 const float* __restrict__ bias, float* __restrict__ out,
                 const ushort* __restrict__ zsrc0,
                 float* __restrict__ gsum, float* __restrict__ gsq)
{
    constexpr int BUF = 16384 + NB * 128;   // ah 8K | al 8K | bh NB*64 | bl NB*64
    constexpr int NI  = NB / 32;            // B frags per wave
    constexpr int BQ  = NB / 64;            // B rows staged per thread
    __shared__ union {
        char s[2 * BUF];
        float c[128][NB + 4];
    } u;
    __shared__ float blkstat[NB][2];

    const int tid  = threadIdx.x;
    const int lane = tid & 63, wv = tid >> 6;
    const int lr = lane & 15, lg = lane >> 4;
    const int wm = wv >> 1,  wn = wv & 1;
    int gx = blockIdx.x;
    gx = (gx & 7) * (gridDim.x >> 3) + (gx >> 3);   // bijective XCD swizzle (grid.x % 8 == 0)
    const int m0 = gx * 128;
    const int n0 = blockIdx.y * NB;

    constexpr int NK  = KTOT / 32;
    constexpr int NKS = NK / SPLITK;
    const int kz = (SPLITK > 1) ? blockIdx.z : 0;
    const int kb = kz * NKS, ke = kb + NKS;
    float* obase = (SPLITK > 1)
        ? out + (size_t)kz * (size_t)gridDim.x * 128 * COUT : out;

    // ---- staging precompute ----
    const int sch = tid & 3;
    int aco[2], apix[2], ay[2] = {0,0}, ax[2] = {0,0};
#pragma unroll
    for (int q = 0; q < 2; q++) {
        int row = (tid >> 2) + q * 64;
        aco[q] = ((sch ^ ((row >> 1) & 3)) << 3);
        int m = m0 + row;
        apix[q] = m;
        if constexpr (IM2COL) {
            int rem = m & (HH * WW - 1);
            ay[q] = rem / WW;
            ax[q] = rem & (WW - 1);
        }
    }
    size_t bbase[BQ];
#pragma unroll
    for (int q = 0; q < BQ; q++) {
        int brow = (tid >> 2) + q * 64;
        bbase[q] = (size_t)(n0 + brow) * KTOT + ((sch ^ ((brow >> 1) & 3)) << 3);
    }

    // ---- fragment read offsets (conflict-free swizzle, verified r4) ----
    const int chunk_p = (lg ^ ((lr >> 1) & 3)) << 4;
    int afoff[4], bfoff[NI];
#pragma unroll
    for (int mi = 0; mi < 4; mi++) afoff[mi] = (wm * 64 + mi * 16 + lr) * 64 + chunk_p;
#pragma unroll
    for (int ni = 0; ni < NI; ni++)
        bfoff[ni] = 16384 + (wn * (NB / 2) + ni * 16 + lr) * 64 + chunk_p;

    float bv[NI];
#pragma unroll
    for (int ni = 0; ni < NI; ni++)
        bv[ni] = BIAS ? bias[n0 + wn * (NB / 2) + ni * 16 + lr] : 0.f;

    f32x4 acc[4][NI] = {};

    auto stage = [&](int kt, int buf) {
        char* dst = u.s + buf * BUF;
        char* dA = dst + wv * 1024;            // + q*4096; lane*16 added by HW
        char* dB = dst + 16384 + wv * 1024;
        if constexpr (IM2COL) {
            int ksp = (kt * 32) / CIN;
            int c0  = (kt * 32) & (CIN - 1);
            int d3  = ksp / 3;
            int dy = d3 - 1, dx = ksp - d3 * 3 - 1;
            int dpix = dy * WW + dx;
#pragma unroll
            for (int q = 0; q < 2; q++) {
                int iy = ay[q] + dy, ix = ax[q] + dx;
                bool ok = ((unsigned)iy < (unsigned)HH) && ((unsigned)ix < (unsigned)WW);
                size_t so = (size_t)(apix[q] + dpix) * CIN + c0 + aco[q];
                gload16(ok ? (const void*)(inH + so) : (const void*)(zsrc0 + aco[q]),
                        dA + q * 4096);
                gload16(ok ? (const void*)(inL + so) : (const void*)(zsrc0 + aco[q]),
                        dA + 8192 + q * 4096);
            }
        } else {
#pragma unroll
            for (int q = 0; q < 2; q++) {
                size_t so = (size_t)apix[q] * KTOT + kt * 32 + aco[q];
                gload16(inH + so, dA + q * 4096);
                gload16(inL + so, dA + 8192 + q * 4096);
            }
        }
#pragma unroll
        for (int q = 0; q < BQ; q++) {
            gload16(wbh + bbase[q] + kt * 32, dB + q * 4096);
            gload16(wbl + bbase[q] + kt * 32, dB + NB * 64 + q * 4096);
        }
    };

    stage(kb, 0);
    __syncthreads();
    int cur = 0;
#pragma unroll 1
    for (int kt = kb; kt < ke; kt++) {
        if (kt + 1 < ke) stage(kt + 1, cur ^ 1);
        const char* base = u.s + cur * BUF;
        s16x8 ah4[4], al4[4], bh2[NI], bl2[NI];
#pragma unroll
        for (int mi = 0; mi < 4; mi++) {
            ah4[mi] = *(const s16x8*)(base + afoff[mi]);
            al4[mi] = *(const s16x8*)(base + afoff[mi] + 8192);
        }
#pragma unroll
        for (int ni = 0; ni < NI; ni++) {
            bh2[ni] = *(const s16x8*)(base + bfoff[ni]);
            bl2[ni] = *(const s16x8*)(base + bfoff[ni] + NB * 64);
        }
        __builtin_amdgcn_s_setprio(1);
#pragma unroll
        for (int mi = 0; mi < 4; mi++)
#pragma unroll
            for (int ni = 0; ni < NI; ni++) {
                acc[mi][ni] = __builtin_amdgcn_mfma_f32_16x16x32_bf16(
                    ah4[mi], bh2[ni], acc[mi][ni], 0, 0, 0);
                acc[mi][ni] = __builtin_amdgcn_mfma_f32_16x16x32_bf16(
                    al4[mi], bh2[ni], acc[mi][ni], 0, 0, 0);
                acc[mi][ni] = __builtin_amdgcn_mfma_f32_16x16x32_bf16(
                    ah4[mi], bl2[ni], acc[mi][ni], 0, 0, 0);
            }
        __builtin_amdgcn_s_setprio(0);
        __syncthreads();   // drains next-tile loads (covered by the MFMA phase) + WAR
        cur ^= 1;
    }

    // ---- epilogue: bias, LDS transpose, store, fused BN stats (+pool) ----
    if (STATS && tid < NB * 2) ((float*)blkstat)[tid] = 0.f;
#pragma unroll
    for (int mi = 0; mi < 4; mi++)
#pragma unroll
        for (int ni = 0; ni < NI; ni++)
#pragma unroll
            for (int r = 0; r < 4; r++)
                u.c[wm * 64 + mi * 16 + lg * 4 + r][wn * (NB / 2) + ni * 16 + lr] =
                    acc[mi][ni][r] + bv[ni];
    __syncthreads();

    constexpr int NCH = NB / 8;        // 8-float chunks per row
    const int chunkE = tid & (NCH - 1), rbE = tid / NCH;
    float ss[8] = {0,0,0,0,0,0,0,0}, qq[8] = {0,0,0,0,0,0,0,0};

    if constexpr (FUSE) {
        // 128-row tile = (128/WW) y-rows; process halves of 64 rows.
        // Each rbE thread-group handles one pooled cell: rows r0,r0+1,r0+WW,r0+WW+1.
        constexpr int XPH = WW / 2;    // pooled-x cells per y-pair group
#pragma unroll
        for (int half = 0; half < 2; half++) {
            const int xp = rbE % XPH, ypl = rbE / XPH;
            const int r0 = half * 64 + ypl * 2 * WW + 2 * xp;
            float vmax[8];
#pragma unroll
            for (int j = 0; j < 8; j++) vmax[j] = -1e30f;
            const int rws[4] = {r0, r0 + 1, r0 + WW, r0 + WW + 1};
#pragma unroll
            for (int i = 0; i < 4; i++) {
                int row = rws[i];
                float v[8];
#pragma unroll
                for (int j = 0; j < 8; j++) {
                    v[j] = u.c[row][chunkE * 8 + j];
                    if (STATS) { ss[j] += v[j]; qq[j] += v[j] * v[j]; }
                    vmax[j] = fmaxf(vmax[j], v[j]);
                }
            }
            int mbase = m0 + half * 64;
            int b  = mbase / (HH * WW);
            int y0 = (mbase % (HH * WW)) / WW;
            size_t po = ((size_t)(b * (HH / 2) + (y0 >> 1) + ypl) * (WW / 2) + xp) * COUT
                        + n0 + chunkE * 8;
            *(float4*)&obase[po]     = make_float4(vmax[0], vmax[1], vmax[2], vmax[3]);
            *(float4*)&obase[po + 4] = make_float4(vmax[4], vmax[5], vmax[6], vmax[7]);
        }
    } else {
        constexpr int RPI = 256 / NCH;     // rows per iteration
        constexpr int ITER = 128 / RPI;
#pragma unroll
        for (int i = 0; i < ITER; i++) {
            int row = rbE + i * RPI;
            float v[8];
#pragma unroll
            for (int j = 0; j < 8; j++) {
                v[j] = u.c[row][chunkE * 8 + j];
                if (STATS) { ss[j] += v[j]; qq[j] += v[j] * v[j]; }
            }
            size_t base = (size_t)(m0 + row) * COUT + n0 + chunkE * 8;
            *(float4*)&obase[base]     = make_float4(v[0], v[1], v[2], v[3]);
            *(float4*)&obase[base + 4] = make_float4(v[4], v[5], v[6], v[7]);
        }
    }
    if (STATS) {
#pragma unroll
        for (int j = 0; j < 8; j++) {
            atomicAdd(&blkstat[chunkE * 8 + j][0], ss[j]);
            atomicAdd(&blkstat[chunkE * 8 + j][1], qq[j]);
        }
        __syncthreads();
        if (tid < NB) {
            atomicAdd(&gsum[n0 + tid], blkstat[tid][0]);
            atomicAdd(&gsq[n0 + tid],  blkstat[tid][1]);
        }
    }
}

// ====== sum P split-K parts (+bias, +BN stats), COUT=256, 8 rows/block =====
template<int P, bool BIASF, bool STATSF>
__global__ __launch_bounds__(256)
void sumk_kernel(const float* __restrict__ parts, size_t pstride,
                 const float* __restrict__ bias, float* __restrict__ outp,
                 float* __restrict__ gsum, float* __restrict__ gsq)
{
    __shared__ float bst[256][2];
    int tid = threadIdx.x;
    if (STATSF) { bst[tid][0] = 0.f; bst[tid][1] = 0.f; __syncthreads(); }
    size_t row = (size_t)blockIdx.x * 8 + (tid >> 5);
    int c0 = (tid & 31) * 8;
    size_t base = row * 256 + c0;
    float v[8];
    float4 a0 = *(const float4*)&parts[base];
    float4 a1 = *(const float4*)&parts[base + 4];
    v[0] = a0.x; v[1] = a0.y; v[2] = a0.z; v[3] = a0.w;
    v[4] = a1.x; v[5] = a1.y; v[6] = a1.z; v[7] = a1.w;
#pragma unroll
    for (int p = 1; p < P; p++) {
        float4 b0 = *(const float4*)&parts[p * pstride + base];
        float4 b1 = *(const float4*)&parts[p * pstride + base + 4];
        v[0] += b0.x; v[1] += b0.y; v[2] += b0.z; v[3] += b0.w;
        v[4] += b1.x; v[5] += b1.y; v[6] += b1.z; v[7] += b1.w;
    }
    if (BIASF) {
#pragma unroll
        for (int j = 0; j < 8; j++) v[j] += bias[c0 + j];
    }
    *(float4*)&outp[base]     = make_float4(v[0], v[1], v[2], v[3]);
    *(float4*)&outp[base + 4] = make_float4(v[4], v[5], v[6], v[7]);
    if (STATSF) {
#pragma unroll
        for (int j = 0; j < 8; j++) {
            atomicAdd(&bst[c0 + j][0], v[j]);
            atomicAdd(&bst[c0 + j][1], v[j] * v[j]);
        }
        __syncthreads();
        atomicAdd(&gsum[tid], bst[tid][0]);
        atomicAdd(&gsq[tid],  bst[tid][1]);
    }
}

// ================= BN finalize: A=g*rsqrt(var+eps), B=b-mu*A ===============
__global__ void bn_finalize(const float* __restrict__ sum, const float* __restrict__ sq,
                            const float* __restrict__ g, const float* __restrict__ b,
                            float* __restrict__ A, float* __restrict__ Bc,
                            int C, float invN)
{
    int c = threadIdx.x;
    if (c < C) {
        float mu  = sum[c] * invN;
        float var = sq[c] * invN - mu * mu;
        float s   = rsqrtf(var + 1e-5f) * g[c];
        A[c]  = s;
        Bc[c] = b[c] - mu * s;
    }
}

// ====== affine+relu+split on pooled fp32 tensor -> bf16 hi/lo planes =======
template<int CC>
__global__ __launch_bounds__(256)
void affine_split_kernel(const float* __restrict__ in, const float* __restrict__ A,
                         const float* __restrict__ Bc, ushort* __restrict__ outH,
                         ushort* __restrict__ outL)
{
    int i = blockIdx.x * 256 + threadIdx.x;
    int c0 = (i & (CC / 8 - 1)) * 8;
    const float* p = in + (size_t)i * 8;
    float4 a0 = *(const float4*)p;
    float4 a1 = *(const float4*)(p + 4);
    float v[8] = {a0.x, a0.y, a0.z, a0.w, a1.x, a1.y, a1.z, a1.w};
    unsigned pwh[4], pwl[4];
#pragma unroll
    for (int jj = 0; jj < 4; jj++) {
        ushort h2[2], l2[2];
#pragma unroll
        for (int k = 0; k < 2; k++) {
            int j = jj * 2 + k;
            int c = c0 + j;
            float m = fmaxf(fmaf(v[j], A[c], Bc[c]), 0.f);
            h2[k] = f2b(m);
            l2[k] = f2b(m - b2f(h2[k]));
        }
        pwh[jj] = (unsigned)h2[0] | ((unsigned)h2[1] << 16);
        pwl[jj] = (unsigned)l2[0] | ((unsigned)l2[1] << 16);
    }
    *(uint4*)&outH[(size_t)i * 8] = make_uint4(pwh[0], pwh[1], pwh[2], pwh[3]);
    *(uint4*)&outL[(size_t)i * 8] = make_uint4(pwl[0], pwl[1], pwl[2], pwl[3]);
}

// ==== BN affine + relu + 2x2 maxpool (fp32 NHWC in -> hi/lo bf16 planes) ===
template<int CC, int HH, int WW>
__global__ __launch_bounds__(256)
void bnpool_kernel(const float* __restrict__ in, const float* __restrict__ A,
                   const float* __restrict__ Bc, ushort* __restrict__ outH,
                   ushort* __restrict__ outL)
{
    constexpr int CH = CC / 8, PW = WW / 2, PH = HH / 2;
    int i = blockIdx.x * 256 + threadIdx.x;
    int cc = i & (CH - 1);
    int t2 = i / CH;
    int px = t2 & (PW - 1);
    int t3 = t2 / PW;
    int py = t3 & (PH - 1);
    int b  = t3 / PH;
    const float* p = in + (size_t)((b * HH + 2 * py) * WW + 2 * px) * CC + cc * 8;
    float v00[8], v01[8], v10[8], v11[8];
#pragma unroll
    for (int j = 0; j < 8; j++) {
        v00[j] = p[j];
        v01[j] = p[CC + j];
        v10[j] = p[(size_t)WW * CC + j];
        v11[j] = p[(size_t)WW * CC + CC + j];
    }
    unsigned pwh[4], pwl[4];
#pragma unroll
    for (int jj = 0; jj < 4; jj++) {
        ushort h2[2], l2[2];
#pragma unroll
        for (int k = 0; k < 2; k++) {
            int j = jj * 2 + k;
            int c = cc * 8 + j;
            float Av = A[c], Bv = Bc[c];
            float m = fmaxf(fmaxf(fmaf(v00[j], Av, Bv), fmaf(v01[j], Av, Bv)),
                            fmaxf(fmaf(v10[j], Av, Bv), fmaf(v11[j], Av, Bv)));
            m = fmaxf(m, 0.f);
            h2[k] = f2b(m);
            l2[k] = f2b(m - b2f(h2[k]));
        }
        pwh[jj] = (unsigned)h2[0] | ((unsigned)h2[1] << 16);
        pwl[jj] = (unsigned)l2[0] | ((unsigned)l2[1] << 16);
    }
    *(uint4*)&outH[(size_t)i * 8] = make_uint4(pwh[0], pwh[1], pwh[2], pwh[3]);
    *(uint4*)&outL[(size_t)i * 8] = make_uint4(pwl[0], pwl[1], pwl[2], pwl[3]);
}

// ======== conv1 (1->64, 64x64, fp32): MODE1 stats / MODE2 pool->planes =====
template<int MODE>
__global__ __launch_bounds__(256)
void conv1_kernel(const float* __restrict__ in, const float* __restrict__ wgt,
                  const float* __restrict__ bias, ushort* __restrict__ outH,
                  ushort* __restrict__ outL,
                  float* __restrict__ ssum, float* __restrict__ ssq,
                  const float* __restrict__ bnA, const float* __restrict__ bnB)
{
    __shared__ float slab[34][34];
    __shared__ float redbuf[4 * 8 * 2];
    const int tid = threadIdx.x;
    const int bg = blockIdx.x >> 2, tile = blockIdx.x & 3;
    const int ty = (tile >> 1) * 32, tx = (tile & 1) * 32;
    const int cout0 = blockIdx.y * 8;
    const int qy = tid >> 4, qx = tid & 15;
    const int oy = ty + 2 * qy, ox = tx + 2 * qx;

    for (int idx = tid; idx < 34 * 34; idx += 256) {
        int sy = idx / 34, sx = idx - sy * 34;
        int gy = ty + sy - 1, gx = tx + sx - 1;
        float v = 0.f;
        if (gy >= 0 && gy < 64 && gx >= 0 && gx < 64)
            v = in[((size_t)bg * 64 + gy) * 64 + gx];
        (&slab[0][0])[idx] = v;
    }
    __syncthreads();
    float v[4][4];
#pragma unroll
    for (int r = 0; r < 4; r++) {
        float2 a = *(const float2*)&slab[2 * qy + r][2 * qx];
        float2 b = *(const float2*)&slab[2 * qy + r][2 * qx + 2];
        v[r][0] = a.x; v[r][1] = a.y; v[r][2] = b.x; v[r][3] = b.y;
    }
    float acc[4][8];
#pragma unroll
    for (int oc = 0; oc < 8; oc++) {
        const float* w9 = wgt + (size_t)(cout0 + oc) * 9;
        float w0 = w9[0], w1 = w9[1], w2 = w9[2], w3 = w9[3], w4 = w9[4],
              w5 = w9[5], w6 = w9[6], w7 = w9[7], w8 = w9[8];
        float bs = bias[cout0 + oc];
#pragma unroll
        for (int dy = 0; dy < 2; dy++)
#pragma unroll
            for (int dx = 0; dx < 2; dx++) {
                float s = bs;
                s = fmaf(w0, v[dy][dx], s);
                s = fmaf(w1, v[dy][dx + 1], s);
                s = fmaf(w2, v[dy][dx + 2], s);
                s = fmaf(w3, v[dy + 1][dx], s);
                s = fmaf(w4, v[dy + 1][dx + 1], s);
                s = fmaf(w5, v[dy + 1][dx + 2], s);
                s = fmaf(w6, v[dy + 2][dx], s);
                s = fmaf(w7, v[dy + 2][dx + 1], s);
                s = fmaf(w8, v[dy + 2][dx + 2], s);
                acc[dy * 2 + dx][oc] = s;
            }
    }
    if constexpr (MODE == 1) {
        int wave = tid >> 6, lanei = tid & 63;
#pragma unroll
        for (int oc = 0; oc < 8; oc++) {
            float s  = acc[0][oc] + acc[1][oc] + acc[2][oc] + acc[3][oc];
            float q2 = acc[0][oc] * acc[0][oc] + acc[1][oc] * acc[1][oc] +
                       acc[2][oc] * acc[2][oc] + acc[3][oc] * acc[3][oc];
#pragma unroll
            for (int off = 32; off > 0; off >>= 1) {
                s  += __shfl_down(s, off);
                q2 += __shfl_down(q2, off);
            }
            if (lanei == 0) {
                redbuf[(wave * 8 + oc) * 2 + 0] = s;
                redbuf[(wave * 8 + oc) * 2 + 1] = q2;
            }
        }
        __syncthreads();
        if (tid < 8) {
            float s = 0.f, q2 = 0.f;
#pragma unroll
            for (int w = 0; w < 4; w++) {
                s  += redbuf[(w * 8 + tid) * 2 + 0];
                q2 += redbuf[(w * 8 + tid) * 2 + 1];
            }
            atomicAdd(&ssum[cout0 + tid], s);
            atomicAdd(&ssq[cout0 + tid], q2);
        }
    }
    if constexpr (MODE == 2) {
        unsigned pwh[4], pwl[4];
#pragma unroll
        for (int jj = 0; jj < 4; jj++) {
            ushort h2[2], l2[2];
#pragma unroll
            for (int k = 0; k < 2; k++) {
                int oc = jj * 2 + k;
                float Av = bnA[cout0 + oc], Bv = bnB[cout0 + oc];
                float m0_ = fmaxf(fmaf(acc[0][oc], Av, Bv), fmaf(acc[1][oc], Av, Bv));
                float m1_ = fmaxf(fmaf(acc[2][oc], Av, Bv), fmaf(acc[3][oc], Av, Bv));
                float m = fmaxf(fmaxf(m0_, m1_), 0.f);
                h2[k] = f2b(m);
                l2[k] = f2b(m - b2f(h2[k]));
            }
            pwh[jj] = (unsigned)h2[0] | ((unsigned)h2[1] << 16);
            pwl[jj] = (unsigned)l2[0] | ((unsigned)l2[1] << 16);
        }
        size_t base = (size_t)((bg * 32 + (oy >> 1)) * 32 + (ox >> 1)) * 64 + cout0;
        *(uint4*)&outH[base] = make_uint4(pwh[0], pwh[1], pwh[2], pwh[3]);
        *(uint4*)&outL[base] = make_uint4(pwl[0], pwl[1], pwl[2], pwl[3]);
    }
}

// =============== offset conv: 256 -> 18 channels at 4x4 (fp32) =============
__global__ __launch_bounds__(256)
void offconv_kernel(const ushort* __restrict__ hH, const ushort* __restrict__ hL,
                    const float* __restrict__ ow, const float* __restrict__ ob,
                    float* __restrict__ off)
{
    __shared__ float plane[256][36];
    int b = blockIdx.x, tid = threadIdx.x;
    for (int i = tid; i < 256 * 36; i += 256) (&plane[0][0])[i] = 0.f;
    __syncthreads();
    for (int i = tid; i < 4096; i += 256) {
        int px = i >> 8, c = i & 255;
        size_t idx = ((size_t)b * 16 + px) * 256 + c;
        plane[c][((px >> 2) + 1) * 6 + (px & 3) + 1] = b2f(hH[idx]) + b2f(hL[idx]);
    }
    __syncthreads();
    for (int o = tid; o < 288; o += 256) {
        int co = o >> 4, px = o & 15, y = px >> 2, x = px & 3;
        float s = ob[co];
        const float* wb = ow + (size_t)co * 256 * 9;
        for (int c = 0; c < 256; c++) {
            const float* wc = wb + c * 9;
            const float* pl = &plane[c][y * 6 + x];
#pragma unroll
            for (int r = 0; r < 3; r++)
#pragma unroll
                for (int k = 0; k < 3; k++)
                    s = fmaf(wc[r * 3 + k], pl[r * 6 + k], s);
        }
        off[((size_t)b * 18 + co) * 16 + px] = s;
    }
}

// ====== deformable sampling -> xo hi/lo bf16 planes [2048][2304] ===========
__global__ __launch_bounds__(256)
void sample_kernel(const ushort* __restrict__ hH, const ushort* __restrict__ hL,
                   const float* __restrict__ off, ushort* __restrict__ xoH,
                   ushort* __restrict__ xoL)
{
    __shared__ float plane[256][36];
    __shared__ int   tidx[144][4];
    __shared__ float twt[144][4];
    int b = blockIdx.x, tid = threadIdx.x;
    for (int i = tid; i < 256 * 36; i += 256) (&plane[0][0])[i] = 0.f;
    __syncthreads();
    for (int i = tid; i < 4096; i += 256) {
        int px = i >> 8, c = i & 255;
        size_t idx = ((size_t)b * 16 + px) * 256 + c;
        plane[c][((px >> 2) + 1) * 6 + (px & 3) + 1] = b2f(hH[idx]) + b2f(hL[idx]);
    }
    if (tid < 144) {
        int px = tid / 9, n = tid % 9;
        int y = px >> 2, x = px & 3;
        float ox_ = off[((size_t)b * 18 + 2 * n) * 16 + px];
        float oy_ = off[((size_t)b * 18 + 2 * n + 1) * 16 + px];
        float pxc = (float)(y + 1) + (float)(n / 3 - 1) + ox_;
        float pyc = (float)(x + 1) + (float)(n % 3 - 1) + oy_;
        if (pxc < 1.f || pxc > 4.f) pxc = floorf(pxc);
        if (pyc < 1.f || pyc > 4.f) pyc = floorf(pyc);
        pxc = fminf(fmaxf(pxc, 0.f), 5.f);
        pyc = fminf(fmaxf(pyc, 0.f), 5.f);
        float fx = floorf(pxc), fy = floorf(pyc);
        float qrbx = fminf(fx + 1.f, 5.f), qrby = fminf(fy + 1.f, 5.f);
        float wx_lt = 1.f + (fx - pxc), wx_rb = 1.f - (qrbx - pxc);
        float wy_lt = 1.f + (fy - pyc), wy_rb = 1.f - (qrby - pyc);
        tidx[tid][0] = (int)(fx * 6.f + fy);     twt[tid][0] = wx_lt * wy_lt;
        tidx[tid][1] = (int)(qrbx * 6.f + qrby); twt[tid][1] = wx_rb * wy_rb;
        tidx[tid][2] = (int)(fx * 6.f + qrby);   twt[tid][2] = wx_lt * wy_rb;
        tidx[tid][3] = (int)(qrbx * 6.f + fy);   twt[tid][3] = wx_rb * wy_lt;
    }
    __syncthreads();
    for (int s = tid; s < 36864; s += 256) {
        int px = s / 2304, k = s - px * 2304;
        int c = k / 9, n = k - c * 9;
        int t = px * 9 + n;
        const float* pc = plane[c];
        float v = twt[t][0] * pc[tidx[t][0]] + twt[t][1] * pc[tidx[t][1]] +
                  twt[t][2] * pc[tidx[t][2]] + twt[t][3] * pc[tidx[t][3]];
        ushort h = f2b(v);
        size_t o = ((size_t)b * 16 + px) * 2304 + k;
        xoH[o] = h;
        xoL[o] = f2b(v - b2f(h));
    }
}

// ============== bn5 stats over relu(dout fp32) =============================
__global__ __launch_bounds__(256)
void stats5_kernel(const float* __restrict__ dout, float* __restrict__ sum5,
                   float* __restrict__ sq5)
{
    __shared__ float rs[256], rq[256];
    int c = blockIdx.x, tid = threadIdx.x;
    float s = 0.f, q = 0.f;
    for (int i = tid; i < 2048; i += 256) {
        float v = fmaxf(dout[(size_t)i * 256 + c], 0.f);
        s += v; q += v * v;
    }
    rs[tid] = s; rq[tid] = q; __syncthreads();
    for (int st = 128; st > 0; st >>= 1) {
        if (tid < st) { rs[tid] += rs[tid + st]; rq[tid] += rq[tid + st]; }
        __syncthreads();
    }
    if (tid == 0) { sum5[c] = rs[0]; sq5[c] = rq[0]; }
}

// ====== head: relu -> bn5 folded into mean -> fc -> log_softmax ============
__global__ __launch_bounds__(256)
void final_kernel(const float* __restrict__ dout, const float* __restrict__ A5,
                  const float* __restrict__ B5, const float* __restrict__ fcw,
                  const float* __restrict__ fcb, float* __restrict__ out)
{
    __shared__ float hbar[256];
    __shared__ float red[256];
    int b = blockIdx.x, tid = threadIdx.x;
    float s = 0.f;
#pragma unroll 4
    for (int px = 0; px < 16; px++)
        s += fmaxf(dout[((size_t)b * 16 + px) * 256 + tid], 0.f);
    hbar[tid] = fmaf(A5[tid], s * (1.f / 16.f), B5[tid]);
    __syncthreads();
    float logit = -1e30f;
    if (tid < 250) {
        float acc = fcb[tid];
        const float4* wr = (const float4*)(fcw + (size_t)tid * 256);
        const float4* hv = (const float4*)hbar;
#pragma unroll 4
        for (int i = 0; i < 64; i++) {
            float4 w4 = wr[i], h4 = hv[i];
            acc = fmaf(w4.x, h4.x, acc); acc = fmaf(w4.y, h4.y, acc);
            acc = fmaf(w4.z, h4.z, acc); acc = fmaf(w4.w, h4.w, acc);
        }
        logit = acc;
    }
    red[tid] = logit; __syncthreads();
    for (int st = 128; st > 0; st >>= 1) {
        if (tid < st) red[tid] = fmaxf(red[tid], red[tid + st]);
        __syncthreads();
    }
    float mx = red[0]; __syncthreads();
    float e = (tid < 250) ? expf(logit - mx) : 0.f;
    red[tid] = e; __syncthreads();
    for (int st = 128; st > 0; st >>= 1) {
        if (tid < st) red[tid] += red[tid + st];
        __syncthreads();
    }
    float lse = logf(red[0]) + mx;
    if (tid < 250) out[(size_t)b * 250 + tid] = logit - lse;
}

// ===========================================================================
extern "C" void kernel_launch(void* const* d_in, const int* in_sizes, int n_in,
                              void* d_out, int out_size, void* d_ws, size_t ws_size,
                              hipStream_t stream)
{
    const float* s_in = (const float*)d_in[0];
    const float* c1w = (const float*)d_in[1];  const float* c1b = (const float*)d_in[2];
    const float* g1  = (const float*)d_in[3];  const float* b1  = (const float*)d_in[4];
    const float* c2w = (const float*)d_in[5];  const float* c2b = (const float*)d_in[6];
    const float* g2  = (const float*)d_in[7];  const float* b2  = (const float*)d_in[8];
    const float* c3w = (const float*)d_in[9];  const float* c3b = (const float*)d_in[10];
    const float* g3  = (const float*)d_in[11]; const float* b3  = (const float*)d_in[12];
    const float* c4w = (const float*)d_in[13]; const float* c4b = (const float*)d_in[14];
    const float* g4  = (const float*)d_in[15]; const float* b4  = (const float*)d_in[16];
    const float* ofw = (const float*)d_in[17]; const float* ofb = (const float*)d_in[18];
    const float* dcw = (const float*)d_in[19];
    const float* g5  = (const float*)d_in[20]; const float* b5  = (const float*)d_in[21];
    const float* fcw = (const float*)d_in[22]; const float* fcb = (const float*)d_in[23];

    float* ws   = (float*)d_ws;
    float* stat = ws;                       // 2560
    float* ab   = ws + 2560;                // 2560
    float* zpad = ws + 5120;                // 64
    ushort* w2h = (ushort*)(ws + 5184);
    ushort* w2l = (ushort*)(ws + 42048);
    ushort* w3h = (ushort*)(ws + 78912);
    ushort* w3l = (ushort*)(ws + 226368);
    ushort* w4h = (ushort*)(ws + 373824);
    ushort* w4l = (ushort*)(ws + 668736);
    ushort* wdh = (ushort*)(ws + 963648);
    ushort* wdl = (ushort*)(ws + 1258560);
    ushort* poolH = (ushort*)(ws + 1553472);   // 8,388,608 u max
    ushort* poolL = (ushort*)(ws + 5747776);
    float*  conv32 = ws + 9942080;             // pooled conv2/conv3 outs (fp32)
    float*  c4parts = ws + 9942080;            // conv4 split-K parts (4 x 2,097,152)
    float*  c4out   = ws + 18330688;           // conv4 summed (2,097,152)
    float*  dparts  = ws + 20427840;           // dconv split-K parts (8 x 524,288)
    ushort* xoH  = (ushort*)(ws + 9942080);    // 4,718,592 u (after conv4 parts dead)
    ushort* xoL  = (ushort*)(ws + 12301376);
    float*  dout = ws + 14660672;              // 524,288 f
    float*  offb = ws + 15184960;              // 36,864 f

    hipMemsetAsync(stat, 0, 2048 * sizeof(float), stream);
    hipMemsetAsync(zpad, 0, 256, stream);

    // weight split-conversions
    wcvt_kernel<<<(128 * 64 * 9 + 255) / 256, 256, 0, stream>>>(c2w, w2h, w2l, 64, 1, 128 * 64 * 9);
    wcvt_kernel<<<(256 * 128 * 9 + 255) / 256, 256, 0, stream>>>(c3w, w3h, w3l, 128, 1, 256 * 128 * 9);
    wcvt_kernel<<<(256 * 256 * 9 + 255) / 256, 256, 0, stream>>>(c4w, w4h, w4l, 256, 1, 256 * 256 * 9);
    wcvt_kernel<<<(256 * 2304 + 255) / 256, 256, 0, stream>>>(dcw, wdh, wdl, 256, 0, 256 * 2304);

    // ---- stage 1: conv1 (recompute trick) -> hi/lo NHWC [B,32,32,64] ----
    conv1_kernel<1><<<dim3(512, 8), 256, 0, stream>>>(s_in, c1w, c1b, nullptr, nullptr,
                                                      stat, stat + 256, nullptr, nullptr);
    bn_finalize<<<1, 256, 0, stream>>>(stat, stat + 256, g1, b1, ab, ab + 256, 64,
                                       1.0f / (128.f * 64.f * 64.f));
    conv1_kernel<2><<<dim3(512, 8), 256, 0, stream>>>(s_in, c1w, c1b, poolH, poolL,
                                                      nullptr, nullptr, ab, ab + 256);

    // ---- stage 2: conv2 GEMM (M=131072, N=128, K=576), fused pool ----
    gemm_kernel<576, 64, 32, 32, 128, true, true, true, 1, 128, true>
        <<<dim3(1024, 1), 256, 0, stream>>>(
        poolH, poolL, w2h, w2l, c2b, conv32, (const ushort*)zpad, stat + 512, stat + 768);
    bn_finalize<<<1, 256, 0, stream>>>(stat + 512, stat + 768, g2, b2, ab + 512, ab + 768,
                                       128, 1.0f / (128.f * 32.f * 32.f));
    affine_split_kernel<128><<<2048, 256, 0, stream>>>(conv32, ab + 512, ab + 768,
                                                       poolH, poolL);

    // ---- stage 3: conv3 GEMM (M=32768, N=256, K=1152), fused pool ----
    gemm_kernel<1152, 128, 16, 16, 256, true, true, true, 1, 128, true>
        <<<dim3(256, 2), 256, 0, stream>>>(
        poolH, poolL, w3h, w3l, c3b, conv32, (const ushort*)zpad, stat + 1024, stat + 1280);
    bn_finalize<<<1, 256, 0, stream>>>(stat + 1024, stat + 1280, g3, b3, ab + 1024, ab + 1280,
                                       256, 1.0f / (128.f * 16.f * 16.f));
    affine_split_kernel<256><<<1024, 256, 0, stream>>>(conv32, ab + 1024, ab + 1280,
                                                       poolH, poolL);

    // ---- stage 4: conv4 GEMM (M=8192, N=256, K=2304), split-K=4 ----
    gemm_kernel<2304, 256, 8, 8, 256, true, false, false, 4, 128, false>
        <<<dim3(64, 2, 4), 256, 0, stream>>>(
        poolH, poolL, w4h, w4l, nullptr, c4parts, (const ushort*)zpad, nullptr, nullptr);
    sumk_kernel<4, true, true><<<1024, 256, 0, stream>>>(
        c4parts, 2097152, c4b, c4out, stat + 1536, stat + 1792);
    bn_finalize<<<1, 256, 0, stream>>>(stat + 1536, stat + 1792, g4, b4, ab + 1536, ab + 1792,
                                       256, 1.0f / (128.f * 8.f * 8.f));
    bnpool_kernel<256, 8, 8><<<256, 256, 0, stream>>>(c4out, ab + 1536, ab + 1792, poolH, poolL);

    // ---- deformable conv (split-K=8) ----
    offconv_kernel<<<128, 256, 0, stream>>>(poolH, poolL, ofw, ofb, offb);
    sample_kernel<<<128, 256, 0, stream>>>(poolH, poolL, offb, xoH, xoL);
    gemm_kernel<2304, 2304, 1, 1, 256, false, false, false, 8, 64, false>
        <<<dim3(16, 4, 8), 256, 0, stream>>>(
        xoH, xoL, wdh, wdl, nullptr, dparts, (const ushort*)zpad, nullptr, nullptr);
    sumk_kernel<8, false, false><<<256, 256, 0, stream>>>(
        dparts, 524288, nullptr, dout, nullptr, nullptr);

    // ---- bn5 + head ----
    stats5_kernel<<<256, 256, 0, stream>>>(dout, stat + 2048, stat + 2304);
    bn_finalize<<<1, 256, 0, stream>>>(stat + 2048, stat + 2304, g5, b5, ab + 2048, ab + 2304,
                                       256, 1.0f / 2048.f);
    final_kernel<<<128, 256, 0, stream>>>(dout, ab + 2048, ab + 2304, fcw, fcb, (float*)d_out);
}

// Round 10
// 369.550 us; speedup vs baseline: 2.7247x; 1.2300x over previous
//
#include <hip/hip_runtime.h>
#include <math.h>

typedef float    f32x4 __attribute__((ext_vector_type(4)));
typedef _Float16 h16x8 __attribute__((ext_vector_type(8)));

__device__ __forceinline__ ushort f2h(float f) {
    _Float16 h = (_Float16)f;
    return *reinterpret_cast<ushort*>(&h);
}
__device__ __forceinline__ float h2f(ushort u) {
    _Float16 h = *reinterpret_cast<_Float16*>(&u);
    return (float)h;
}
__device__ __forceinline__ void gload16(const void* g, void* l) {
    __builtin_amdgcn_global_load_lds((const __attribute__((address_space(1))) void*)g,
                                     (__attribute__((address_space(3))) void*)l, 16, 0, 0);
}

// ====== weight convert: fp32 OIHW -> fp16 [CO][ksp*CI+ci] ==================
__global__ __launch_bounds__(256)
void wcvt_kernel(const float* __restrict__ src, ushort* __restrict__ dst,
                 int CI, int reorder, int total)
{
    int i = blockIdx.x * 256 + threadIdx.x;
    if (i >= total) return;
    float v;
    if (reorder) {
        int k9 = CI * 9;
        int co = i / k9; int rem = i - co * k9;
        int ksp = rem / CI; int ci = rem - ksp * CI;
        v = src[(size_t)(co * CI + ci) * 9 + ksp];
    } else {
        v = src[i];
    }
    dst[i] = f2h(v);
}

// ================= fp16 MFMA implicit-GEMM (2-phase, r6 schedule) ==========
// A+B staged in LDS via global_load_lds, 2-buffer stage-ahead. BM=128, BN=NB;
// 4 waves 2x2, wave tile 64 x NB/2, BK=32. Single fp16 (no hi/lo split).
// FUSE: epilogue 2x2-maxpools pre-BN values (valid: BN A>0 commutes w/ pool);
// BN stats still over ALL pre-pool values. Half-pass epilogue keeps LDS ~34KB.
template<int KTOT, int CIN, int HH, int WW, int COUT, bool IM2COL, bool BIAS,
         bool STATS, int SPLITK, int NB, bool FUSE>
__global__ __launch_bounds__(256, 3)
void gemm_kernel(const ushort* __restrict__ in16, const ushort* __restrict__ wb16,
                 const float* __restrict__ bias, float* __restrict__ out,
                 const ushort* __restrict__ zsrc0,
                 float* __restrict__ gsum, float* __restrict__ gsq)
{
    constexpr int ABYTES = 8192;            // 128 rows x 64B (BK=32 fp16)
    constexpr int BBYTES = NB * 64;
    constexpr int BUF = ABYTES + BBYTES;
    constexpr int NI  = NB / 32;            // B frags per wave
    constexpr int BQ  = NB / 64;            // B rows staged per thread
    __shared__ union {
        char s[2 * BUF];
        float c2[64][NB + 4];               // half-pass epilogue transpose
    } u;
    __shared__ float blkstat[NB][2];

    const int tid  = threadIdx.x;
    const int lane = tid & 63, wv = tid >> 6;
    const int lr = lane & 15, lg = lane >> 4;
    const int wm = wv >> 1,  wn = wv & 1;
    int gx = blockIdx.x;
    gx = (gx & 7) * (gridDim.x >> 3) + (gx >> 3);   // bijective XCD swizzle (grid.x % 8 == 0)
    const int m0 = gx * 128;
    const int n0 = blockIdx.y * NB;

    constexpr int NK  = KTOT / 32;
    constexpr int NKS = NK / SPLITK;
    const int kz = (SPLITK > 1) ? blockIdx.z : 0;
    const int kb = kz * NKS, ke = kb + NKS;
    float* obase = (SPLITK > 1)
        ? out + (size_t)kz * (size_t)gridDim.x * 128 * COUT : out;

    // ---- staging precompute ----
    const int sch = tid & 3;
    int aco[2], apix[2], ay[2] = {0,0}, ax[2] = {0,0};
#pragma unroll
    for (int q = 0; q < 2; q++) {
        int row = (tid >> 2) + q * 64;
        aco[q] = ((sch ^ ((row >> 1) & 3)) << 3);   // swizzled source elem offset
        int m = m0 + row;
        apix[q] = m;
        if constexpr (IM2COL) {
            int rem = m & (HH * WW - 1);
            ay[q] = rem / WW;
            ax[q] = rem & (WW - 1);
        }
    }
    size_t bbase[BQ];
#pragma unroll
    for (int q = 0; q < BQ; q++) {
        int brow = (tid >> 2) + q * 64;
        bbase[q] = (size_t)(n0 + brow) * KTOT + ((sch ^ ((brow >> 1) & 3)) << 3);
    }

    // ---- fragment read offsets (conflict-free swizzle, verified r4) ----
    const int chunk_p = (lg ^ ((lr >> 1) & 3)) << 4;
    int afoff[4], bfoff[NI];
#pragma unroll
    for (int mi = 0; mi < 4; mi++) afoff[mi] = (wm * 64 + mi * 16 + lr) * 64 + chunk_p;
#pragma unroll
    for (int ni = 0; ni < NI; ni++)
        bfoff[ni] = ABYTES + (wn * (NB / 2) + ni * 16 + lr) * 64 + chunk_p;

    float bv[NI];
#pragma unroll
    for (int ni = 0; ni < NI; ni++)
        bv[ni] = BIAS ? bias[n0 + wn * (NB / 2) + ni * 16 + lr] : 0.f;

    f32x4 acc[4][NI] = {};

    auto stage = [&](int kt, int buf) {
        char* dst = u.s + buf * BUF;
        char* dA = dst + wv * 1024;            // + q*4096; lane*16 added by HW
        char* dB = dst + ABYTES + wv * 1024;
        if constexpr (IM2COL) {
            int ksp = (kt * 32) / CIN;
            int c0  = (kt * 32) & (CIN - 1);
            int d3  = ksp / 3;
            int dy = d3 - 1, dx = ksp - d3 * 3 - 1;
            int dpix = dy * WW + dx;
#pragma unroll
            for (int q = 0; q < 2; q++) {
                int iy = ay[q] + dy, ix = ax[q] + dx;
                bool ok = ((unsigned)iy < (unsigned)HH) && ((unsigned)ix < (unsigned)WW);
                size_t so = (size_t)(apix[q] + dpix) * CIN + c0 + aco[q];
                gload16(ok ? (const void*)(in16 + so) : (const void*)(zsrc0 + aco[q]),
                        dA + q * 4096);
            }
        } else {
#pragma unroll
            for (int q = 0; q < 2; q++) {
                size_t so = (size_t)apix[q] * KTOT + kt * 32 + aco[q];
                gload16(in16 + so, dA + q * 4096);
            }
        }
#pragma unroll
        for (int q = 0; q < BQ; q++)
            gload16(wb16 + bbase[q] + kt * 32, dB + q * 4096);
    };

    stage(kb, 0);
    __syncthreads();
    int cur = 0;
#pragma unroll 1
    for (int kt = kb; kt < ke; kt++) {
        if (kt + 1 < ke) stage(kt + 1, cur ^ 1);
        const char* base = u.s + cur * BUF;
        h16x8 a4[4], b4[NI];
#pragma unroll
        for (int mi = 0; mi < 4; mi++) a4[mi] = *(const h16x8*)(base + afoff[mi]);
#pragma unroll
        for (int ni = 0; ni < NI; ni++) b4[ni] = *(const h16x8*)(base + bfoff[ni]);
        __builtin_amdgcn_s_setprio(1);
#pragma unroll
        for (int mi = 0; mi < 4; mi++)
#pragma unroll
            for (int ni = 0; ni < NI; ni++)
                acc[mi][ni] = __builtin_amdgcn_mfma_f32_16x16x32_f16(
                    a4[mi], b4[ni], acc[mi][ni], 0, 0, 0);
        __builtin_amdgcn_s_setprio(0);
        __syncthreads();   // drains next-tile loads (covered by MFMA phase) + WAR
        cur ^= 1;
    }

    // ---- epilogue: bias, half-pass LDS transpose, store, BN stats (+pool) --
    if (STATS && tid < NB * 2) ((float*)blkstat)[tid] = 0.f;
    constexpr int NCH = NB / 8;
    const int chunkE = tid & (NCH - 1), rbE = tid / NCH;
    float ss[8] = {0,0,0,0,0,0,0,0}, qq[8] = {0,0,0,0,0,0,0,0};
#pragma unroll
    for (int half = 0; half < 2; half++) {
        __syncthreads();
        if (wm == half) {
#pragma unroll
            for (int mi = 0; mi < 4; mi++)
#pragma unroll
                for (int ni = 0; ni < NI; ni++)
#pragma unroll
                    for (int r = 0; r < 4; r++)
                        u.c2[mi * 16 + lg * 4 + r][wn * (NB / 2) + ni * 16 + lr] =
                            acc[mi][ni][r] + bv[ni];
        }
        __syncthreads();
        if constexpr (FUSE) {
            constexpr int XPH = WW / 2;
            const int xp = rbE % XPH, ypl = rbE / XPH;
            const int r0 = ypl * 2 * WW + 2 * xp;
            float vmax[8];
#pragma unroll
            for (int j = 0; j < 8; j++) vmax[j] = -1e30f;
            const int rws[4] = {r0, r0 + 1, r0 + WW, r0 + WW + 1};
#pragma unroll
            for (int i = 0; i < 4; i++) {
                int row = rws[i];
                float v[8];
#pragma unroll
                for (int j = 0; j < 8; j++) {
                    v[j] = u.c2[row][chunkE * 8 + j];
                    if (STATS) { ss[j] += v[j]; qq[j] += v[j] * v[j]; }
                    vmax[j] = fmaxf(vmax[j], v[j]);
                }
            }
            int mbase = m0 + half * 64;
            int b  = mbase / (HH * WW);
            int y0 = (mbase % (HH * WW)) / WW;
            size_t po = ((size_t)(b * (HH / 2) + (y0 >> 1) + ypl) * (WW / 2) + xp) * COUT
                        + n0 + chunkE * 8;
            *(float4*)&obase[po]     = make_float4(vmax[0], vmax[1], vmax[2], vmax[3]);
            *(float4*)&obase[po + 4] = make_float4(vmax[4], vmax[5], vmax[6], vmax[7]);
        } else {
            constexpr int RPI = 256 / NCH;
            constexpr int ITER = 64 / RPI;
#pragma unroll
            for (int i = 0; i < ITER; i++) {
                int row = rbE + i * RPI;
                float v[8];
#pragma unroll
                for (int j = 0; j < 8; j++) {
                    v[j] = u.c2[row][chunkE * 8 + j];
                    if (STATS) { ss[j] += v[j]; qq[j] += v[j] * v[j]; }
                }
                size_t base = (size_t)(m0 + half * 64 + row) * COUT + n0 + chunkE * 8;
                *(float4*)&obase[base]     = make_float4(v[0], v[1], v[2], v[3]);
                *(float4*)&obase[base + 4] = make_float4(v[4], v[5], v[6], v[7]);
            }
        }
    }
    if (STATS) {
#pragma unroll
        for (int j = 0; j < 8; j++) {
            atomicAdd(&blkstat[chunkE * 8 + j][0], ss[j]);
            atomicAdd(&blkstat[chunkE * 8 + j][1], qq[j]);
        }
        __syncthreads();
        if (tid < NB) {
            atomicAdd(&gsum[n0 + tid], blkstat[tid][0]);
            atomicAdd(&gsq[n0 + tid],  blkstat[tid][1]);
        }
    }
}

// ====== sum P split-K parts (+bias, +BN stats), COUT=256, 8 rows/block =====
template<int P, bool BIASF, bool STATSF>
__global__ __launch_bounds__(256)
void sumk_kernel(const float* __restrict__ parts, size_t pstride,
                 const float* __restrict__ bias, float* __restrict__ outp,
                 float* __restrict__ gsum, float* __restrict__ gsq)
{
    __shared__ float bst[256][2];
    int tid = threadIdx.x;
    if (STATSF) { bst[tid][0] = 0.f; bst[tid][1] = 0.f; __syncthreads(); }
    size_t row = (size_t)blockIdx.x * 8 + (tid >> 5);
    int c0 = (tid & 31) * 8;
    size_t base = row * 256 + c0;
    float v[8];
    float4 a0 = *(const float4*)&parts[base];
    float4 a1 = *(const float4*)&parts[base + 4];
    v[0] = a0.x; v[1] = a0.y; v[2] = a0.z; v[3] = a0.w;
    v[4] = a1.x; v[5] = a1.y; v[6] = a1.z; v[7] = a1.w;
#pragma unroll
    for (int p = 1; p < P; p++) {
        float4 b0 = *(const float4*)&parts[p * pstride + base];
        float4 b1 = *(const float4*)&parts[p * pstride + base + 4];
        v[0] += b0.x; v[1] += b0.y; v[2] += b0.z; v[3] += b0.w;
        v[4] += b1.x; v[5] += b1.y; v[6] += b1.z; v[7] += b1.w;
    }
    if (BIASF) {
#pragma unroll
        for (int j = 0; j < 8; j++) v[j] += bias[c0 + j];
    }
    *(float4*)&outp[base]     = make_float4(v[0], v[1], v[2], v[3]);
    *(float4*)&outp[base + 4] = make_float4(v[4], v[5], v[6], v[7]);
    if (STATSF) {
#pragma unroll
        for (int j = 0; j < 8; j++) {
            atomicAdd(&bst[c0 + j][0], v[j]);
            atomicAdd(&bst[c0 + j][1], v[j] * v[j]);
        }
        __syncthreads();
        atomicAdd(&gsum[tid], bst[tid][0]);
        atomicAdd(&gsq[tid],  bst[tid][1]);
    }
}

// ================= BN finalize: A=g*rsqrt(var+eps), B=b-mu*A ===============
__global__ void bn_finalize(const float* __restrict__ sum, const float* __restrict__ sq,
                            const float* __restrict__ g, const float* __restrict__ b,
                            float* __restrict__ A, float* __restrict__ Bc,
                            int C, float invN)
{
    int c = threadIdx.x;
    if (c < C) {
        float mu  = sum[c] * invN;
        float var = sq[c] * invN - mu * mu;
        float s   = rsqrtf(var + 1e-5f) * g[c];
        A[c]  = s;
        Bc[c] = b[c] - mu * s;
    }
}

// ====== affine+relu on pooled fp32 tensor -> fp16 ==========================
template<int CC>
__global__ __launch_bounds__(256)
void affine_split_kernel(const float* __restrict__ in, const float* __restrict__ A,
                         const float* __restrict__ Bc, ushort* __restrict__ outH)
{
    int i = blockIdx.x * 256 + threadIdx.x;
    int c0 = (i & (CC / 8 - 1)) * 8;
    const float* p = in + (size_t)i * 8;
    float4 a0 = *(const float4*)p;
    float4 a1 = *(const float4*)(p + 4);
    float v[8] = {a0.x, a0.y, a0.z, a0.w, a1.x, a1.y, a1.z, a1.w};
    unsigned pw[4];
#pragma unroll
    for (int jj = 0; jj < 4; jj++) {
        ushort h2[2];
#pragma unroll
        for (int k = 0; k < 2; k++) {
            int j = jj * 2 + k;
            int c = c0 + j;
            h2[k] = f2h(fmaxf(fmaf(v[j], A[c], Bc[c]), 0.f));
        }
        pw[jj] = (unsigned)h2[0] | ((unsigned)h2[1] << 16);
    }
    *(uint4*)&outH[(size_t)i * 8] = make_uint4(pw[0], pw[1], pw[2], pw[3]);
}

// ==== BN affine + relu + 2x2 maxpool (fp32 NHWC in -> fp16) ================
template<int CC, int HH, int WW>
__global__ __launch_bounds__(256)
void bnpool_kernel(const float* __restrict__ in, const float* __restrict__ A,
                   const float* __restrict__ Bc, ushort* __restrict__ outH)
{
    constexpr int CH = CC / 8, PW = WW / 2, PH = HH / 2;
    int i = blockIdx.x * 256 + threadIdx.x;
    int cc = i & (CH - 1);
    int t2 = i / CH;
    int px = t2 & (PW - 1);
    int t3 = t2 / PW;
    int py = t3 & (PH - 1);
    int b  = t3 / PH;
    const float* p = in + (size_t)((b * HH + 2 * py) * WW + 2 * px) * CC + cc * 8;
    float v00[8], v01[8], v10[8], v11[8];
#pragma unroll
    for (int j = 0; j < 8; j++) {
        v00[j] = p[j];
        v01[j] = p[CC + j];
        v10[j] = p[(size_t)WW * CC + j];
        v11[j] = p[(size_t)WW * CC + CC + j];
    }
    unsigned pw[4];
#pragma unroll
    for (int jj = 0; jj < 4; jj++) {
        ushort h2[2];
#pragma unroll
        for (int k = 0; k < 2; k++) {
            int j = jj * 2 + k;
            int c = cc * 8 + j;
            float Av = A[c], Bv = Bc[c];
            float m = fmaxf(fmaxf(fmaf(v00[j], Av, Bv), fmaf(v01[j], Av, Bv)),
                            fmaxf(fmaf(v10[j], Av, Bv), fmaf(v11[j], Av, Bv)));
            h2[k] = f2h(fmaxf(m, 0.f));
        }
        pw[jj] = (unsigned)h2[0] | ((unsigned)h2[1] << 16);
    }
    *(uint4*)&outH[(size_t)i * 8] = make_uint4(pw[0], pw[1], pw[2], pw[3]);
}

// ======== conv1 (1->64, 64x64, fp32): MODE1 stats / MODE2 pool->fp16 =======
template<int MODE>
__global__ __launch_bounds__(256)
void conv1_kernel(const float* __restrict__ in, const float* __restrict__ wgt,
                  const float* __restrict__ bias, ushort* __restrict__ outH,
                  float* __restrict__ ssum, float* __restrict__ ssq,
                  const float* __restrict__ bnA, const float* __restrict__ bnB)
{
    __shared__ float slab[34][34];
    __shared__ float redbuf[4 * 8 * 2];
    const int tid = threadIdx.x;
    const int bg = blockIdx.x >> 2, tile = blockIdx.x & 3;
    const int ty = (tile >> 1) * 32, tx = (tile & 1) * 32;
    const int cout0 = blockIdx.y * 8;
    const int qy = tid >> 4, qx = tid & 15;
    const int oy = ty + 2 * qy, ox = tx + 2 * qx;

    for (int idx = tid; idx < 34 * 34; idx += 256) {
        int sy = idx / 34, sx = idx - sy * 34;
        int gy = ty + sy - 1, gx = tx + sx - 1;
        float v = 0.f;
        if (gy >= 0 && gy < 64 && gx >= 0 && gx < 64)
            v = in[((size_t)bg * 64 + gy) * 64 + gx];
        (&slab[0][0])[idx] = v;
    }
    __syncthreads();
    float v[4][4];
#pragma unroll
    for (int r = 0; r < 4; r++) {
        float2 a = *(const float2*)&slab[2 * qy + r][2 * qx];
        float2 b = *(const float2*)&slab[2 * qy + r][2 * qx + 2];
        v[r][0] = a.x; v[r][1] = a.y; v[r][2] = b.x; v[r][3] = b.y;
    }
    float acc[4][8];
#pragma unroll
    for (int oc = 0; oc < 8; oc++) {
        const float* w9 = wgt + (size_t)(cout0 + oc) * 9;
        float w0 = w9[0], w1 = w9[1], w2 = w9[2], w3 = w9[3], w4 = w9[4],
              w5 = w9[5], w6 = w9[6], w7 = w9[7], w8 = w9[8];
        float bs = bias[cout0 + oc];
#pragma unroll
        for (int dy = 0; dy < 2; dy++)
#pragma unroll
            for (int dx = 0; dx < 2; dx++) {
                float s = bs;
                s = fmaf(w0, v[dy][dx], s);
                s = fmaf(w1, v[dy][dx + 1], s);
                s = fmaf(w2, v[dy][dx + 2], s);
                s = fmaf(w3, v[dy + 1][dx], s);
                s = fmaf(w4, v[dy + 1][dx + 1], s);
                s = fmaf(w5, v[dy + 1][dx + 2], s);
                s = fmaf(w6, v[dy + 2][dx], s);
                s = fmaf(w7, v[dy + 2][dx + 1], s);
                s = fmaf(w8, v[dy + 2][dx + 2], s);
                acc[dy * 2 + dx][oc] = s;
            }
    }
    if constexpr (MODE == 1) {
        int wave = tid >> 6, lanei = tid & 63;
#pragma unroll
        for (int oc = 0; oc < 8; oc++) {
            float s  = acc[0][oc] + acc[1][oc] + acc[2][oc] + acc[3][oc];
            float q2 = acc[0][oc] * acc[0][oc] + acc[1][oc] * acc[1][oc] +
                       acc[2][oc] * acc[2][oc] + acc[3][oc] * acc[3][oc];
#pragma unroll
            for (int off = 32; off > 0; off >>= 1) {
                s  += __shfl_down(s, off);
                q2 += __shfl_down(q2, off);
            }
            if (lanei == 0) {
                redbuf[(wave * 8 + oc) * 2 + 0] = s;
                redbuf[(wave * 8 + oc) * 2 + 1] = q2;
            }
        }
        __syncthreads();
        if (tid < 8) {
            float s = 0.f, q2 = 0.f;
#pragma unroll
            for (int w = 0; w < 4; w++) {
                s  += redbuf[(w * 8 + tid) * 2 + 0];
                q2 += redbuf[(w * 8 + tid) * 2 + 1];
            }
            atomicAdd(&ssum[cout0 + tid], s);
            atomicAdd(&ssq[cout0 + tid], q2);
        }
    }
    if constexpr (MODE == 2) {
        unsigned pw[4];
#pragma unroll
        for (int jj = 0; jj < 4; jj++) {
            ushort h2[2];
#pragma unroll
            for (int k = 0; k < 2; k++) {
                int oc = jj * 2 + k;
                float Av = bnA[cout0 + oc], Bv = bnB[cout0 + oc];
                float m0_ = fmaxf(fmaf(acc[0][oc], Av, Bv), fmaf(acc[1][oc], Av, Bv));
                float m1_ = fmaxf(fmaf(acc[2][oc], Av, Bv), fmaf(acc[3][oc], Av, Bv));
                h2[k] = f2h(fmaxf(fmaxf(m0_, m1_), 0.f));
            }
            pw[jj] = (unsigned)h2[0] | ((unsigned)h2[1] << 16);
        }
        size_t base = (size_t)((bg * 32 + (oy >> 1)) * 32 + (ox >> 1)) * 64 + cout0;
        *(uint4*)&outH[base] = make_uint4(pw[0], pw[1], pw[2], pw[3]);
    }
}

// =============== offset conv: 256 -> 18 channels at 4x4 (fp32) =============
__global__ __launch_bounds__(256)
void offconv_kernel(const ushort* __restrict__ hH, const float* __restrict__ ow,
                    const float* __restrict__ ob, float* __restrict__ off)
{
    __shared__ float plane[256][36];
    int b = blockIdx.x, tid = threadIdx.x;
    for (int i = tid; i < 256 * 36; i += 256) (&plane[0][0])[i] = 0.f;
    __syncthreads();
    for (int i = tid; i < 4096; i += 256) {
        int px = i >> 8, c = i & 255;
        plane[c][((px >> 2) + 1) * 6 + (px & 3) + 1] = h2f(hH[((size_t)b * 16 + px) * 256 + c]);
    }
    __syncthreads();
    for (int o = tid; o < 288; o += 256) {
        int co = o >> 4, px = o & 15, y = px >> 2, x = px & 3;
        float s = ob[co];
        const float* wb = ow + (size_t)co * 256 * 9;
        for (int c = 0; c < 256; c++) {
            const float* wc = wb + c * 9;
            const float* pl = &plane[c][y * 6 + x];
#pragma unroll
            for (int r = 0; r < 3; r++)
#pragma unroll
                for (int k = 0; k < 3; k++)
                    s = fmaf(wc[r * 3 + k], pl[r * 6 + k], s);
        }
        off[((size_t)b * 18 + co) * 16 + px] = s;
    }
}

// ====== deformable sampling -> xo fp16 [2048][2304] ========================
__global__ __launch_bounds__(256)
void sample_kernel(const ushort* __restrict__ hH, const float* __restrict__ off,
                   ushort* __restrict__ xoH)
{
    __shared__ float plane[256][36];
    __shared__ int   tidx[144][4];
    __shared__ float twt[144][4];
    int b = blockIdx.x, tid = threadIdx.x;
    for (int i = tid; i < 256 * 36; i += 256) (&plane[0][0])[i] = 0.f;
    __syncthreads();
    for (int i = tid; i < 4096; i += 256) {
        int px = i >> 8, c = i & 255;
        plane[c][((px >> 2) + 1) * 6 + (px & 3) + 1] = h2f(hH[((size_t)b * 16 + px) * 256 + c]);
    }
    if (tid < 144) {
        int px = tid / 9, n = tid % 9;
        int y = px >> 2, x = px & 3;
        float ox_ = off[((size_t)b * 18 + 2 * n) * 16 + px];
        float oy_ = off[((size_t)b * 18 + 2 * n + 1) * 16 + px];
        float pxc = (float)(y + 1) + (float)(n / 3 - 1) + ox_;
        float pyc = (float)(x + 1) + (float)(n % 3 - 1) + oy_;
        if (pxc < 1.f || pxc > 4.f) pxc = floorf(pxc);
        if (pyc < 1.f || pyc > 4.f) pyc = floorf(pyc);
        pxc = fminf(fmaxf(pxc, 0.f), 5.f);
        pyc = fminf(fmaxf(pyc, 0.f), 5.f);
        float fx = floorf(pxc), fy = floorf(pyc);
        float qrbx = fminf(fx + 1.f, 5.f), qrby = fminf(fy + 1.f, 5.f);
        float wx_lt = 1.f + (fx - pxc), wx_rb = 1.f - (qrbx - pxc);
        float wy_lt = 1.f + (fy - pyc), wy_rb = 1.f - (qrby - pyc);
        tidx[tid][0] = (int)(fx * 6.f + fy);     twt[tid][0] = wx_lt * wy_lt;
        tidx[tid][1] = (int)(qrbx * 6.f + qrby); twt[tid][1] = wx_rb * wy_rb;
        tidx[tid][2] = (int)(fx * 6.f + qrby);   twt[tid][2] = wx_lt * wy_rb;
        tidx[tid][3] = (int)(qrbx * 6.f + fy);   twt[tid][3] = wx_rb * wy_lt;
    }
    __syncthreads();
    for (int s = tid; s < 36864; s += 256) {
        int px = s / 2304, k = s - px * 2304;
        int c = k / 9, n = k - c * 9;
        int t = px * 9 + n;
        const float* pc = plane[c];
        float v = twt[t][0] * pc[tidx[t][0]] + twt[t][1] * pc[tidx[t][1]] +
                  twt[t][2] * pc[tidx[t][2]] + twt[t][3] * pc[tidx[t][3]];
        xoH[((size_t)b * 16 + px) * 2304 + k] = f2h(v);
    }
}

// ============== bn5 stats over relu(dout fp32) =============================
__global__ __launch_bounds__(256)
void stats5_kernel(const float* __restrict__ dout, float* __restrict__ sum5,
                   float* __restrict__ sq5)
{
    __shared__ float rs[256], rq[256];
    int c = blockIdx.x, tid = threadIdx.x;
    float s = 0.f, q = 0.f;
    for (int i = tid; i < 2048; i += 256) {
        float v = fmaxf(dout[(size_t)i * 256 + c], 0.f);
        s += v; q += v * v;
    }
    rs[tid] = s; rq[tid] = q; __syncthreads();
    for (int st = 128; st > 0; st >>= 1) {
        if (tid < st) { rs[tid] += rs[tid + st]; rq[tid] += rq[tid + st]; }
        __syncthreads();
    }
    if (tid == 0) { sum5[c] = rs[0]; sq5[c] = rq[0]; }
}

// ====== head: relu -> bn5 folded into mean -> fc -> log_softmax ============
__global__ __launch_bounds__(256)
void final_kernel(const float* __restrict__ dout, const float* __restrict__ A5,
                  const float* __restrict__ B5, const float* __restrict__ fcw,
                  const float* __restrict__ fcb, float* __restrict__ out)
{
    __shared__ float hbar[256];
    __shared__ float red[256];
    int b = blockIdx.x, tid = threadIdx.x;
    float s = 0.f;
#pragma unroll 4
    for (int px = 0; px < 16; px++)
        s += fmaxf(dout[((size_t)b * 16 + px) * 256 + tid], 0.f);
    hbar[tid] = fmaf(A5[tid], s * (1.f / 16.f), B5[tid]);
    __syncthreads();
    float logit = -1e30f;
    if (tid < 250) {
        float acc = fcb[tid];
        const float4* wr = (const float4*)(fcw + (size_t)tid * 256);
        const float4* hv = (const float4*)hbar;
#pragma unroll 4
        for (int i = 0; i < 64; i++) {
            float4 w4 = wr[i], h4 = hv[i];
            acc = fmaf(w4.x, h4.x, acc); acc = fmaf(w4.y, h4.y, acc);
            acc = fmaf(w4.z, h4.z, acc); acc = fmaf(w4.w, h4.w, acc);
        }
        logit = acc;
    }
    red[tid] = logit; __syncthreads();
    for (int st = 128; st > 0; st >>= 1) {
        if (tid < st) red[tid] = fmaxf(red[tid], red[tid + st]);
        __syncthreads();
    }
    float mx = red[0]; __syncthreads();
    float e = (tid < 250) ? expf(logit - mx) : 0.f;
    red[tid] = e; __syncthreads();
    for (int st = 128; st > 0; st >>= 1) {
        if (tid < st) red[tid] += red[tid + st];
        __syncthreads();
    }
    float lse = logf(red[0]) + mx;
    if (tid < 250) out[(size_t)b * 250 + tid] = logit - lse;
}

// ===========================================================================
extern "C" void kernel_launch(void* const* d_in, const int* in_sizes, int n_in,
                              void* d_out, int out_size, void* d_ws, size_t ws_size,
                              hipStream_t stream)
{
    const float* s_in = (const float*)d_in[0];
    const float* c1w = (const float*)d_in[1];  const float* c1b = (const float*)d_in[2];
    const float* g1  = (const float*)d_in[3];  const float* b1  = (const float*)d_in[4];
    const float* c2w = (const float*)d_in[5];  const float* c2b = (const float*)d_in[6];
    const float* g2  = (const float*)d_in[7];  const float* b2  = (const float*)d_in[8];
    const float* c3w = (const float*)d_in[9];  const float* c3b = (const float*)d_in[10];
    const float* g3  = (const float*)d_in[11]; const float* b3  = (const float*)d_in[12];
    const float* c4w = (const float*)d_in[13]; const float* c4b = (const float*)d_in[14];
    const float* g4  = (const float*)d_in[15]; const float* b4  = (const float*)d_in[16];
    const float* ofw = (const float*)d_in[17]; const float* ofb = (const float*)d_in[18];
    const float* dcw = (const float*)d_in[19];
    const float* g5  = (const float*)d_in[20]; const float* b5  = (const float*)d_in[21];
    const float* fcw = (const float*)d_in[22]; const float* fcb = (const float*)d_in[23];

    float* ws   = (float*)d_ws;
    float* stat = ws;                       // 2560
    float* ab   = ws + 2560;                // 2560
    float* zpad = ws + 5120;                // 64
    ushort* w2  = (ushort*)(ws + 5184);     // 73728 u
    ushort* w3  = (ushort*)(ws + 78912);    // 294912 u
    ushort* w4  = (ushort*)(ws + 373824);   // 589824 u
    ushort* wd  = (ushort*)(ws + 963648);   // 589824 u
    ushort* pool16 = (ushort*)(ws + 1553472);  // 8,388,608 u max
    float*  conv32 = ws + 9942080;             // pooled conv2/conv3 outs (fp32)
    float*  c4parts = ws + 9942080;            // conv4 split-K parts (4 x 2,097,152)
    float*  c4out   = ws + 18330688;           // conv4 summed (2,097,152)
    float*  dparts  = ws + 20427840;           // dconv split-K parts (8 x 524,288)
    ushort* xo16 = (ushort*)(ws + 9942080);    // 4,718,592 u (after conv4 parts dead)
    float*  dout = ws + 14660672;              // 524,288 f
    float*  offb = ws + 15184960;              // 36,864 f

    hipMemsetAsync(stat, 0, 2048 * sizeof(float), stream);
    hipMemsetAsync(zpad, 0, 256, stream);

    // weight conversions (fp32 -> fp16, OHWI reorder for convs, direct for dconv)
    wcvt_kernel<<<(128 * 64 * 9 + 255) / 256, 256, 0, stream>>>(c2w, w2, 64, 1, 128 * 64 * 9);
    wcvt_kernel<<<(256 * 128 * 9 + 255) / 256, 256, 0, stream>>>(c3w, w3, 128, 1, 256 * 128 * 9);
    wcvt_kernel<<<(256 * 256 * 9 + 255) / 256, 256, 0, stream>>>(c4w, w4, 256, 1, 256 * 256 * 9);
    wcvt_kernel<<<(256 * 2304 + 255) / 256, 256, 0, stream>>>(dcw, wd, 256, 0, 256 * 2304);

    // ---- stage 1: conv1 (recompute trick) -> fp16 NHWC [B,32,32,64] ----
    conv1_kernel<1><<<dim3(512, 8), 256, 0, stream>>>(s_in, c1w, c1b, nullptr,
                                                      stat, stat + 256, nullptr, nullptr);
    bn_finalize<<<1, 256, 0, stream>>>(stat, stat + 256, g1, b1, ab, ab + 256, 64,
                                       1.0f / (128.f * 64.f * 64.f));
    conv1_kernel<2><<<dim3(512, 8), 256, 0, stream>>>(s_in, c1w, c1b, pool16,
                                                      nullptr, nullptr, ab, ab + 256);

    // ---- stage 2: conv2 GEMM (M=131072, N=128, K=576), fused pool ----
    gemm_kernel<576, 64, 32, 32, 128, true, true, true, 1, 128, true>
        <<<dim3(1024, 1), 256, 0, stream>>>(
        pool16, w2, c2b, conv32, (const ushort*)zpad, stat + 512, stat + 768);
    bn_finalize<<<1, 256, 0, stream>>>(stat + 512, stat + 768, g2, b2, ab + 512, ab + 768,
                                       128, 1.0f / (128.f * 32.f * 32.f));
    affine_split_kernel<128><<<2048, 256, 0, stream>>>(conv32, ab + 512, ab + 768, pool16);

    // ---- stage 3: conv3 GEMM (M=32768, N=256, K=1152), fused pool ----
    gemm_kernel<1152, 128, 16, 16, 256, true, true, true, 1, 128, true>
        <<<dim3(256, 2), 256, 0, stream>>>(
        pool16, w3, c3b, conv32, (const ushort*)zpad, stat + 1024, stat + 1280);
    bn_finalize<<<1, 256, 0, stream>>>(stat + 1024, stat + 1280, g3, b3, ab + 1024, ab + 1280,
                                       256, 1.0f / (128.f * 16.f * 16.f));
    affine_split_kernel<256><<<1024, 256, 0, stream>>>(conv32, ab + 1024, ab + 1280, pool16);

    // ---- stage 4: conv4 GEMM (M=8192, N=256, K=2304), split-K=4 ----
    gemm_kernel<2304, 256, 8, 8, 256, true, false, false, 4, 128, false>
        <<<dim3(64, 2, 4), 256, 0, stream>>>(
        pool16, w4, nullptr, c4parts, (const ushort*)zpad, nullptr, nullptr);
    sumk_kernel<4, true, true><<<1024, 256, 0, stream>>>(
        c4parts, 2097152, c4b, c4out, stat + 1536, stat + 1792);
    bn_finalize<<<1, 256, 0, stream>>>(stat + 1536, stat + 1792, g4, b4, ab + 1536, ab + 1792,
                                       256, 1.0f / (128.f * 8.f * 8.f));
    bnpool_kernel<256, 8, 8><<<256, 256, 0, stream>>>(c4out, ab + 1536, ab + 1792, pool16);

    // ---- deformable conv (split-K=8) ----
    offconv_kernel<<<128, 256, 0, stream>>>(pool16, ofw, ofb, offb);
    sample_kernel<<<128, 256, 0, stream>>>(pool16, offb, xo16);
    gemm_kernel<2304, 2304, 1, 1, 256, false, false, false, 8, 64, false>
        <<<dim3(16, 4, 8), 256, 0, stream>>>(
        xo16, wd, nullptr, dparts, (const ushort*)zpad, nullptr, nullptr);
    sumk_kernel<8, false, false><<<256, 256, 0, stream>>>(
        dparts, 524288, nullptr, dout, nullptr, nullptr);

    // ---- bn5 + head ----
    stats5_kernel<<<256, 256, 0, stream>>>(dout, stat + 2048, stat + 2304);
    bn_finalize<<<1, 256, 0, stream>>>(stat + 2048, stat + 2304, g5, b5, ab + 2048, ab + 2304,
                                       256, 1.0f / 2048.f);
    final_kernel<<<128, 256, 0, stream>>>(dout, ab + 2048, ab + 2304, fcw, fcb, (float*)d_out);
}

// Round 13
// 344.164 us; speedup vs baseline: 2.9257x; 1.0738x over previous
//
#include <hip/hip_runtime.h>
#include <math.h>

typedef float    f32x4 __attribute__((ext_vector_type(4)));
typedef _Float16 h16x8 __attribute__((ext_vector_type(8)));

__device__ __forceinline__ ushort f2h(float f) {
    _Float16 h = (_Float16)f;
    return *reinterpret_cast<ushort*>(&h);
}
__device__ __forceinline__ float h2f(ushort u) {
    _Float16 h = *reinterpret_cast<_Float16*>(&u);
    return (float)h;
}
__device__ __forceinline__ void gload16(const void* g, void* l) {
    __builtin_amdgcn_global_load_lds((const __attribute__((address_space(1))) void*)g,
                                     (__attribute__((address_space(3))) void*)l, 16, 0, 0);
}

// ====== weight convert: fp32 OIHW -> fp16 [CO][ksp*CI+ci] ==================
__global__ __launch_bounds__(256)
void wcvt_kernel(const float* __restrict__ src, ushort* __restrict__ dst,
                 int CI, int reorder, int total)
{
    int i = blockIdx.x * 256 + threadIdx.x;
    if (i >= total) return;
    float v;
    if (reorder) {
        int k9 = CI * 9;
        int co = i / k9; int rem = i - co * k9;
        int ksp = rem / CI; int ci = rem - ksp * CI;
        v = src[(size_t)(co * CI + ci) * 9 + ksp];
    } else {
        v = src[i];
    }
    dst[i] = f2h(v);
}

// ================= fp16 MFMA implicit-GEMM (2-phase, r6 schedule) ==========
template<int KTOT, int CIN, int HH, int WW, int COUT, bool IM2COL, bool BIAS,
         bool STATS, int SPLITK, int NB, bool FUSE>
__global__ __launch_bounds__(256, 3)
void gemm_kernel(const ushort* __restrict__ in16, const ushort* __restrict__ wb16,
                 const float* __restrict__ bias, float* __restrict__ out,
                 const ushort* __restrict__ zsrc0,
                 float* __restrict__ gsum, float* __restrict__ gsq)
{
    constexpr int ABYTES = 8192;            // 128 rows x 64B (BK=32 fp16)
    constexpr int BBYTES = NB * 64;
    constexpr int BUF = ABYTES + BBYTES;
    constexpr int NI  = NB / 32;            // B frags per wave
    constexpr int BQ  = NB / 64;            // B rows staged per thread
    __shared__ union {
        char s[2 * BUF];
        float c2[64][NB + 4];               // half-pass epilogue transpose
    } u;
    __shared__ float blkstat[NB][2];

    const int tid  = threadIdx.x;
    const int lane = tid & 63, wv = tid >> 6;
    const int lr = lane & 15, lg = lane >> 4;
    const int wm = wv >> 1,  wn = wv & 1;
    int gx = blockIdx.x;
    gx = (gx & 7) * (gridDim.x >> 3) + (gx >> 3);   // bijective XCD swizzle (grid.x % 8 == 0)
    const int m0 = gx * 128;
    const int n0 = blockIdx.y * NB;

    constexpr int NK  = KTOT / 32;
    constexpr int NKS = NK / SPLITK;
    const int kz = (SPLITK > 1) ? blockIdx.z : 0;
    const int kb = kz * NKS, ke = kb + NKS;
    float* obase = (SPLITK > 1)
        ? out + (size_t)kz * (size_t)gridDim.x * 128 * COUT : out;

    // ---- staging precompute ----
    const int sch = tid & 3;
    int aco[2], apix[2], ay[2] = {0,0}, ax[2] = {0,0};
#pragma unroll
    for (int q = 0; q < 2; q++) {
        int row = (tid >> 2) + q * 64;
        aco[q] = ((sch ^ ((row >> 1) & 3)) << 3);   // swizzled source elem offset
        int m = m0 + row;
        apix[q] = m;
        if constexpr (IM2COL) {
            int rem = m & (HH * WW - 1);
            ay[q] = rem / WW;
            ax[q] = rem & (WW - 1);
        }
    }
    size_t bbase[BQ];
#pragma unroll
    for (int q = 0; q < BQ; q++) {
        int brow = (tid >> 2) + q * 64;
        bbase[q] = (size_t)(n0 + brow) * KTOT + ((sch ^ ((brow >> 1) & 3)) << 3);
    }

    // ---- fragment read offsets (conflict-free swizzle, verified r4) ----
    const int chunk_p = (lg ^ ((lr >> 1) & 3)) << 4;
    int afoff[4], bfoff[NI];
#pragma unroll
    for (int mi = 0; mi < 4; mi++) afoff[mi] = (wm * 64 + mi * 16 + lr) * 64 + chunk_p;
#pragma unroll
    for (int ni = 0; ni < NI; ni++)
        bfoff[ni] = ABYTES + (wn * (NB / 2) + ni * 16 + lr) * 64 + chunk_p;

    float bv[NI];
#pragma unroll
    for (int ni = 0; ni < NI; ni++)
        bv[ni] = BIAS ? bias[n0 + wn * (NB / 2) + ni * 16 + lr] : 0.f;

    f32x4 acc[4][NI] = {};

    auto stage = [&](int kt, int buf) {
        char* dst = u.s + buf * BUF;
        char* dA = dst + wv * 1024;            // + q*4096; lane*16 added by HW
        char* dB = dst + ABYTES + wv * 1024;
        if constexpr (IM2COL) {
            int ksp = (kt * 32) / CIN;
            int c0  = (kt * 32) & (CIN - 1);
            int d3  = ksp / 3;
            int dy = d3 - 1, dx = ksp - d3 * 3 - 1;
            int dpix = dy * WW + dx;
#pragma unroll
            for (int q = 0; q < 2; q++) {
                int iy = ay[q] + dy, ix = ax[q] + dx;
                bool ok = ((unsigned)iy < (unsigned)HH) && ((unsigned)ix < (unsigned)WW);
                size_t so = (size_t)(apix[q] + dpix) * CIN + c0 + aco[q];
                gload16(ok ? (const void*)(in16 + so) : (const void*)(zsrc0 + aco[q]),
                        dA + q * 4096);
            }
        } else {
#pragma unroll
            for (int q = 0; q < 2; q++) {
                size_t so = (size_t)apix[q] * KTOT + kt * 32 + aco[q];
                gload16(in16 + so, dA + q * 4096);
            }
        }
#pragma unroll
        for (int q = 0; q < BQ; q++)
            gload16(wb16 + bbase[q] + kt * 32, dB + q * 4096);
    };

    stage(kb, 0);
    __syncthreads();
    int cur = 0;
#pragma unroll 1
    for (int kt = kb; kt < ke; kt++) {
        if (kt + 1 < ke) stage(kt + 1, cur ^ 1);
        const char* base = u.s + cur * BUF;
        h16x8 a4[4], b4[NI];
#pragma unroll
        for (int mi = 0; mi < 4; mi++) a4[mi] = *(const h16x8*)(base + afoff[mi]);
#pragma unroll
        for (int ni = 0; ni < NI; ni++) b4[ni] = *(const h16x8*)(base + bfoff[ni]);
        __builtin_amdgcn_s_setprio(1);
#pragma unroll
        for (int mi = 0; mi < 4; mi++)
#pragma unroll
            for (int ni = 0; ni < NI; ni++)
                acc[mi][ni] = __builtin_amdgcn_mfma_f32_16x16x32_f16(
                    a4[mi], b4[ni], acc[mi][ni], 0, 0, 0);
        __builtin_amdgcn_s_setprio(0);
        __syncthreads();   // drains next-tile loads (covered by MFMA phase) + WAR
        cur ^= 1;
    }

    // ---- epilogue: bias, half-pass LDS transpose, store, BN stats (+pool) --
    if (STATS && tid < NB * 2) ((float*)blkstat)[tid] = 0.f;
    constexpr int NCH = NB / 8;
    const int chunkE = tid & (NCH - 1), rbE = tid / NCH;
    float ss[8] = {0,0,0,0,0,0,0,0}, qq[8] = {0,0,0,0,0,0,0,0};
#pragma unroll
    for (int half = 0; half < 2; half++) {
        __syncthreads();
        if (wm == half) {
#pragma unroll
            for (int mi = 0; mi < 4; mi++)
#pragma unroll
                for (int ni = 0; ni < NI; ni++)
#pragma unroll
                    for (int r = 0; r < 4; r++)
                        u.c2[mi * 16 + lg * 4 + r][wn * (NB / 2) + ni * 16 + lr] =
                            acc[mi][ni][r] + bv[ni];
        }
        __syncthreads();
        if constexpr (FUSE) {
            constexpr int XPH = WW / 2;
            const int xp = rbE % XPH, ypl = rbE / XPH;
            const int r0 = ypl * 2 * WW + 2 * xp;
            float vmax[8];
#pragma unroll
            for (int j = 0; j < 8; j++) vmax[j] = -1e30f;
            const int rws[4] = {r0, r0 + 1, r0 + WW, r0 + WW + 1};
#pragma unroll
            for (int i = 0; i < 4; i++) {
                int row = rws[i];
                float v[8];
#pragma unroll
                for (int j = 0; j < 8; j++) {
                    v[j] = u.c2[row][chunkE * 8 + j];
                    if (STATS) { ss[j] += v[j]; qq[j] += v[j] * v[j]; }
                    vmax[j] = fmaxf(vmax[j], v[j]);
                }
            }
            int mbase = m0 + half * 64;
            int b  = mbase / (HH * WW);
            int y0 = (mbase % (HH * WW)) / WW;
            size_t po = ((size_t)(b * (HH / 2) + (y0 >> 1) + ypl) * (WW / 2) + xp) * COUT
                        + n0 + chunkE * 8;
            *(float4*)&obase[po]     = make_float4(vmax[0], vmax[1], vmax[2], vmax[3]);
            *(float4*)&obase[po + 4] = make_float4(vmax[4], vmax[5], vmax[6], vmax[7]);
        } else {
            constexpr int RPI = 256 / NCH;
            constexpr int ITER = 64 / RPI;
#pragma unroll
            for (int i = 0; i < ITER; i++) {
                int row = rbE + i * RPI;
                float v[8];
#pragma unroll
                for (int j = 0; j < 8; j++) {
                    v[j] = u.c2[row][chunkE * 8 + j];
                    if (STATS) { ss[j] += v[j]; qq[j] += v[j] * v[j]; }
                }
                size_t base = (size_t)(m0 + half * 64 + row) * COUT + n0 + chunkE * 8;
                *(float4*)&obase[base]     = make_float4(v[0], v[1], v[2], v[3]);
                *(float4*)&obase[base + 4] = make_float4(v[4], v[5], v[6], v[7]);
            }
        }
    }
    if (STATS) {
#pragma unroll
        for (int j = 0; j < 8; j++) {
            atomicAdd(&blkstat[chunkE * 8 + j][0], ss[j]);
            atomicAdd(&blkstat[chunkE * 8 + j][1], qq[j]);
        }
        __syncthreads();
        if (tid < NB) {
            atomicAdd(&gsum[n0 + tid], blkstat[tid][0]);
            atomicAdd(&gsq[n0 + tid],  blkstat[tid][1]);
        }
    }
}

// ====== sum P split-K parts (+bias, +BN stats), COUT=256, 8 rows/block =====
template<int P, bool BIASF, bool STATSF>
__global__ __launch_bounds__(256)
void sumk_kernel(const float* __restrict__ parts, size_t pstride,
                 const float* __restrict__ bias, float* __restrict__ outp,
                 float* __restrict__ gsum, float* __restrict__ gsq)
{
    __shared__ float bst[256][2];
    int tid = threadIdx.x;
    if (STATSF) { bst[tid][0] = 0.f; bst[tid][1] = 0.f; __syncthreads(); }
    size_t row = (size_t)blockIdx.x * 8 + (tid >> 5);
    int c0 = (tid & 31) * 8;
    size_t base = row * 256 + c0;
    float v[8];
    float4 a0 = *(const float4*)&parts[base];
    float4 a1 = *(const float4*)&parts[base + 4];
    v[0] = a0.x; v[1] = a0.y; v[2] = a0.z; v[3] = a0.w;
    v[4] = a1.x; v[5] = a1.y; v[6] = a1.z; v[7] = a1.w;
#pragma unroll
    for (int p = 1; p < P; p++) {
        float4 b0 = *(const float4*)&parts[p * pstride + base];
        float4 b1 = *(const float4*)&parts[p * pstride + base + 4];
        v[0] += b0.x; v[1] += b0.y; v[2] += b0.z; v[3] += b0.w;
        v[4] += b1.x; v[5] += b1.y; v[6] += b1.z; v[7] += b1.w;
    }
    if (BIASF) {
#pragma unroll
        for (int j = 0; j < 8; j++) v[j] += bias[c0 + j];
    }
    *(float4*)&outp[base]     = make_float4(v[0], v[1], v[2], v[3]);
    *(float4*)&outp[base + 4] = make_float4(v[4], v[5], v[6], v[7]);
    if (STATSF) {
#pragma unroll
        for (int j = 0; j < 8; j++) {
            atomicAdd(&bst[c0 + j][0], v[j]);
            atomicAdd(&bst[c0 + j][1], v[j] * v[j]);
        }
        __syncthreads();
        atomicAdd(&gsum[tid], bst[tid][0]);
        atomicAdd(&gsq[tid],  bst[tid][1]);
    }
}

// ================= BN finalize: A=g*rsqrt(var+eps), B=b-mu*A ===============
__global__ void bn_finalize(const float* __restrict__ sum, const float* __restrict__ sq,
                            const float* __restrict__ g, const float* __restrict__ b,
                            float* __restrict__ A, float* __restrict__ Bc,
                            int C, float invN)
{
    int c = threadIdx.x;
    if (c < C) {
        float mu  = sum[c] * invN;
        float var = sq[c] * invN - mu * mu;
        float s   = rsqrtf(var + 1e-5f) * g[c];
        A[c]  = s;
        Bc[c] = b[c] - mu * s;
    }
}

// ====== affine+relu on pooled fp32 tensor -> fp16 ==========================
template<int CC>
__global__ __launch_bounds__(256)
void affine_split_kernel(const float* __restrict__ in, const float* __restrict__ A,
                         const float* __restrict__ Bc, ushort* __restrict__ outH)
{
    int i = blockIdx.x * 256 + threadIdx.x;
    int c0 = (i & (CC / 8 - 1)) * 8;
    const float* p = in + (size_t)i * 8;
    float4 a0 = *(const float4*)p;
    float4 a1 = *(const float4*)(p + 4);
    float v[8] = {a0.x, a0.y, a0.z, a0.w, a1.x, a1.y, a1.z, a1.w};
    unsigned pw[4];
#pragma unroll
    for (int jj = 0; jj < 4; jj++) {
        ushort h2[2];
#pragma unroll
        for (int k = 0; k < 2; k++) {
            int j = jj * 2 + k;
            int c = c0 + j;
            h2[k] = f2h(fmaxf(fmaf(v[j], A[c], Bc[c]), 0.f));
        }
        pw[jj] = (unsigned)h2[0] | ((unsigned)h2[1] << 16);
    }
    *(uint4*)&outH[(size_t)i * 8] = make_uint4(pw[0], pw[1], pw[2], pw[3]);
}

// ==== BN affine + relu + 2x2 maxpool (fp32 NHWC in -> fp16) ================
template<int CC, int HH, int WW>
__global__ __launch_bounds__(256)
void bnpool_kernel(const float* __restrict__ in, const float* __restrict__ A,
                   const float* __restrict__ Bc, ushort* __restrict__ outH)
{
    constexpr int CH = CC / 8, PW = WW / 2, PH = HH / 2;
    int i = blockIdx.x * 256 + threadIdx.x;
    int cc = i & (CH - 1);
    int t2 = i / CH;
    int px = t2 & (PW - 1);
    int t3 = t2 / PW;
    int py = t3 & (PH - 1);
    int b  = t3 / PH;
    const float* p = in + (size_t)((b * HH + 2 * py) * WW + 2 * px) * CC + cc * 8;
    float v00[8], v01[8], v10[8], v11[8];
#pragma unroll
    for (int j = 0; j < 8; j++) {
        v00[j] = p[j];
        v01[j] = p[CC + j];
        v10[j] = p[(size_t)WW * CC + j];
        v11[j] = p[(size_t)WW * CC + CC + j];
    }
    unsigned pw[4];
#pragma unroll
    for (int jj = 0; jj < 4; jj++) {
        ushort h2[2];
#pragma unroll
        for (int k = 0; k < 2; k++) {
            int j = jj * 2 + k;
            int c = cc * 8 + j;
            float Av = A[c], Bv = Bc[c];
            float m = fmaxf(fmaxf(fmaf(v00[j], Av, Bv), fmaf(v01[j], Av, Bv)),
                            fmaxf(fmaf(v10[j], Av, Bv), fmaf(v11[j], Av, Bv)));
            h2[k] = f2h(fmaxf(m, 0.f));
        }
        pw[jj] = (unsigned)h2[0] | ((unsigned)h2[1] << 16);
    }
    *(uint4*)&outH[(size_t)i * 8] = make_uint4(pw[0], pw[1], pw[2], pw[3]);
}

// ======== conv1 (1->64, 64x64, fp32): MODE1 stats / MODE2 pool->fp16 =======
template<int MODE>
__global__ __launch_bounds__(256)
void conv1_kernel(const float* __restrict__ in, const float* __restrict__ wgt,
                  const float* __restrict__ bias, ushort* __restrict__ outH,
                  float* __restrict__ ssum, float* __restrict__ ssq,
                  const float* __restrict__ bnA, const float* __restrict__ bnB)
{
    __shared__ float slab[34][34];
    __shared__ float redbuf[4 * 8 * 2];
    const int tid = threadIdx.x;
    const int bg = blockIdx.x >> 2, tile = blockIdx.x & 3;
    const int ty = (tile >> 1) * 32, tx = (tile & 1) * 32;
    const int cout0 = blockIdx.y * 8;
    const int qy = tid >> 4, qx = tid & 15;
    const int oy = ty + 2 * qy, ox = tx + 2 * qx;

    for (int idx = tid; idx < 34 * 34; idx += 256) {
        int sy = idx / 34, sx = idx - sy * 34;
        int gy = ty + sy - 1, gx = tx + sx - 1;
        float v = 0.f;
        if (gy >= 0 && gy < 64 && gx >= 0 && gx < 64)
            v = in[((size_t)bg * 64 + gy) * 64 + gx];
        (&slab[0][0])[idx] = v;
    }
    __syncthreads();
    float v[4][4];
#pragma unroll
    for (int r = 0; r < 4; r++) {
        float2 a = *(const float2*)&slab[2 * qy + r][2 * qx];
        float2 b = *(const float2*)&slab[2 * qy + r][2 * qx + 2];
        v[r][0] = a.x; v[r][1] = a.y; v[r][2] = b.x; v[r][3] = b.y;
    }
    float acc[4][8];
#pragma unroll
    for (int oc = 0; oc < 8; oc++) {
        const float* w9 = wgt + (size_t)(cout0 + oc) * 9;
        float w0 = w9[0], w1 = w9[1], w2 = w9[2], w3 = w9[3], w4 = w9[4],
              w5 = w9[5], w6 = w9[6], w7 = w9[7], w8 = w9[8];
        float bs = bias[cout0 + oc];
#pragma unroll
        for (int dy = 0; dy < 2; dy++)
#pragma unroll
            for (int dx = 0; dx < 2; dx++) {
                float s = bs;
                s = fmaf(w0, v[dy][dx], s);
                s = fmaf(w1, v[dy][dx + 1], s);
                s = fmaf(w2, v[dy][dx + 2], s);
                s = fmaf(w3, v[dy + 1][dx], s);
                s = fmaf(w4, v[dy + 1][dx + 1], s);
                s = fmaf(w5, v[dy + 1][dx + 2], s);
                s = fmaf(w6, v[dy + 2][dx], s);
                s = fmaf(w7, v[dy + 2][dx + 1], s);
                s = fmaf(w8, v[dy + 2][dx + 2], s);
                acc[dy * 2 + dx][oc] = s;
            }
    }
    if constexpr (MODE == 1) {
        int wave = tid >> 6, lanei = tid & 63;
#pragma unroll
        for (int oc = 0; oc < 8; oc++) {
            float s  = acc[0][oc] + acc[1][oc] + acc[2][oc] + acc[3][oc];
            float q2 = acc[0][oc] * acc[0][oc] + acc[1][oc] * acc[1][oc] +
                       acc[2][oc] * acc[2][oc] + acc[3][oc] * acc[3][oc];
#pragma unroll
            for (int off = 32; off > 0; off >>= 1) {
                s  += __shfl_down(s, off);
                q2 += __shfl_down(q2, off);
            }
            if (lanei == 0) {
                redbuf[(wave * 8 + oc) * 2 + 0] = s;
                redbuf[(wave * 8 + oc) * 2 + 1] = q2;
            }
        }
        __syncthreads();
        if (tid < 8) {
            float s = 0.f, q2 = 0.f;
#pragma unroll
            for (int w = 0; w < 4; w++) {
                s  += redbuf[(w * 8 + tid) * 2 + 0];
                q2 += redbuf[(w * 8 + tid) * 2 + 1];
            }
            atomicAdd(&ssum[cout0 + tid], s);
            atomicAdd(&ssq[cout0 + tid], q2);
        }
    }
    if constexpr (MODE == 2) {
        unsigned pw[4];
#pragma unroll
        for (int jj = 0; jj < 4; jj++) {
            ushort h2[2];
#pragma unroll
            for (int k = 0; k < 2; k++) {
                int oc = jj * 2 + k;
                float Av = bnA[cout0 + oc], Bv = bnB[cout0 + oc];
                float m0_ = fmaxf(fmaf(acc[0][oc], Av, Bv), fmaf(acc[1][oc], Av, Bv));
                float m1_ = fmaxf(fmaf(acc[2][oc], Av, Bv), fmaf(acc[3][oc], Av, Bv));
                h2[k] = f2h(fmaxf(fmaxf(m0_, m1_), 0.f));
            }
            pw[jj] = (unsigned)h2[0] | ((unsigned)h2[1] << 16);
        }
        size_t base = (size_t)((bg * 32 + (oy >> 1)) * 32 + (ox >> 1)) * 64 + cout0;
        *(uint4*)&outH[base] = make_uint4(pw[0], pw[1], pw[2], pw[3]);
    }
}

// ====== offset conv (r10 arithmetic order, split grid): 256->18 at 4x4 =====
// grid (128 b, 2 halves); each thread computes AT MOST ONE output o with the
// EXACT serial c-major/n-minor single-accumulator order of the r10 version
// (bit-identical offsets -- the mask/floor path downstream is discontinuous).
__global__ __launch_bounds__(256)
void offconv_kernel(const ushort* __restrict__ hH, const float* __restrict__ ow,
                    const float* __restrict__ ob, float* __restrict__ off)
{
    __shared__ float plane[256][36];
    int b = blockIdx.x, half = blockIdx.y, tid = threadIdx.x;
    for (int i = tid; i < 256 * 36; i += 256) (&plane[0][0])[i] = 0.f;
    __syncthreads();
    for (int i = tid; i < 4096; i += 256) {
        int px = i >> 8, c = i & 255;
        plane[c][((px >> 2) + 1) * 6 + (px & 3) + 1] =
            h2f(hH[((size_t)b * 16 + px) * 256 + c]);
    }
    __syncthreads();
    if (tid < 144) {
        int o = half * 144 + tid;
        int co = o >> 4, px = o & 15, y = px >> 2, x = px & 3;
        float s = ob[co];
        const float* wb = ow + (size_t)co * 256 * 9;
        for (int c = 0; c < 256; c++) {
            const float* wc = wb + c * 9;
            const float* pl = &plane[c][y * 6 + x];
#pragma unroll
            for (int r = 0; r < 3; r++)
#pragma unroll
                for (int k = 0; k < 3; k++)
                    s = fmaf(wc[r * 3 + k], pl[r * 6 + k], s);
        }
        off[((size_t)b * 18 + co) * 16 + px] = s;
    }
}

// ====== deformable sampling -> xo fp16 [2048][2304] ========================
__global__ __launch_bounds__(256)
void sample_kernel(const ushort* __restrict__ hH, const float* __restrict__ off,
                   ushort* __restrict__ xoH)
{
    __shared__ float plane[256][36];
    __shared__ int   tidx[144][4];
    __shared__ float twt[144][4];
    int b = blockIdx.x, tid = threadIdx.x;
    for (int i = tid; i < 256 * 36; i += 256) (&plane[0][0])[i] = 0.f;
    __syncthreads();
    for (int i = tid; i < 4096; i += 256) {
        int px = i >> 8, c = i & 255;
        plane[c][((px >> 2) + 1) * 6 + (px & 3) + 1] = h2f(hH[((size_t)b * 16 + px) * 256 + c]);
    }
    if (tid < 144) {
        int px = tid / 9, n = tid % 9;
        int y = px >> 2, x = px & 3;
        float ox_ = off[((size_t)b * 18 + 2 * n) * 16 + px];
        float oy_ = off[((size_t)b * 18 + 2 * n + 1) * 16 + px];
        float pxc = (float)(y + 1) + (float)(n / 3 - 1) + ox_;
        float pyc = (float)(x + 1) + (float)(n % 3 - 1) + oy_;
        if (pxc < 1.f || pxc > 4.f) pxc = floorf(pxc);
        if (pyc < 1.f || pyc > 4.f) pyc = floorf(pyc);
        pxc = fminf(fmaxf(pxc, 0.f), 5.f);
        pyc = fminf(fmaxf(pyc, 0.f), 5.f);
        float fx = floorf(pxc), fy = floorf(pyc);
        float qrbx = fminf(fx + 1.f, 5.f), qrby = fminf(fy + 1.f, 5.f);
        float wx_lt = 1.f + (fx - pxc), wx_rb = 1.f - (qrbx - pxc);
        float wy_lt = 1.f + (fy - pyc), wy_rb = 1.f - (qrby - pyc);
        tidx[tid][0] = (int)(fx * 6.f + fy);     twt[tid][0] = wx_lt * wy_lt;
        tidx[tid][1] = (int)(qrbx * 6.f + qrby); twt[tid][1] = wx_rb * wy_rb;
        tidx[tid][2] = (int)(fx * 6.f + qrby);   twt[tid][2] = wx_lt * wy_rb;
        tidx[tid][3] = (int)(qrbx * 6.f + fy);   twt[tid][3] = wx_rb * wy_lt;
    }
    __syncthreads();
    for (int s = tid; s < 36864; s += 256) {
        int px = s / 2304, k = s - px * 2304;
        int c = k / 9, n = k - c * 9;
        int t = px * 9 + n;
        const float* pc = plane[c];
        float v = twt[t][0] * pc[tidx[t][0]] + twt[t][1] * pc[tidx[t][1]] +
                  twt[t][2] * pc[tidx[t][2]] + twt[t][3] * pc[tidx[t][3]];
        xoH[((size_t)b * 16 + px) * 2304 + k] = f2h(v);
    }
}

// ============== bn5 stats over relu(dout fp32) =============================
__global__ __launch_bounds__(256)
void stats5_kernel(const float* __restrict__ dout, float* __restrict__ sum5,
                   float* __restrict__ sq5)
{
    __shared__ float rs[256], rq[256];
    int c = blockIdx.x, tid = threadIdx.x;
    float s = 0.f, q = 0.f;
    for (int i = tid; i < 2048; i += 256) {
        float v = fmaxf(dout[(size_t)i * 256 + c], 0.f);
        s += v; q += v * v;
    }
    rs[tid] = s; rq[tid] = q; __syncthreads();
    for (int st = 128; st > 0; st >>= 1) {
        if (tid < st) { rs[tid] += rs[tid + st]; rq[tid] += rq[tid + st]; }
        __syncthreads();
    }
    if (tid == 0) { sum5[c] = rs[0]; sq5[c] = rq[0]; }
}

// ====== head: relu -> bn5 folded into mean -> fc -> log_softmax ============
__global__ __launch_bounds__(256)
void final_kernel(const float* __restrict__ dout, const float* __restrict__ A5,
                  const float* __restrict__ B5, const float* __restrict__ fcw,
                  const float* __restrict__ fcb, float* __restrict__ out)
{
    __shared__ float hbar[256];
    __shared__ float red[256];
    int b = blockIdx.x, tid = threadIdx.x;
    float s = 0.f;
#pragma unroll 4
    for (int px = 0; px < 16; px++)
        s += fmaxf(dout[((size_t)b * 16 + px) * 256 + tid], 0.f);
    hbar[tid] = fmaf(A5[tid], s * (1.f / 16.f), B5[tid]);
    __syncthreads();
    float logit = -1e30f;
    if (tid < 250) {
        float acc = fcb[tid];
        const float4* wr = (const float4*)(fcw + (size_t)tid * 256);
        const float4* hv = (const float4*)hbar;
#pragma unroll 4
        for (int i = 0; i < 64; i++) {
            float4 w4 = wr[i], h4 = hv[i];
            acc = fmaf(w4.x, h4.x, acc); acc = fmaf(w4.y, h4.y, acc);
            acc = fmaf(w4.z, h4.z, acc); acc = fmaf(w4.w, h4.w, acc);
        }
        logit = acc;
    }
    red[tid] = logit; __syncthreads();
    for (int st = 128; st > 0; st >>= 1) {
        if (tid < st) red[tid] = fmaxf(red[tid], red[tid + st]);
        __syncthreads();
    }
    float mx = red[0]; __syncthreads();
    float e = (tid < 250) ? expf(logit - mx) : 0.f;
    red[tid] = e; __syncthreads();
    for (int st = 128; st > 0; st >>= 1) {
        if (tid < st) red[tid] += red[tid + st];
        __syncthreads();
    }
    float lse = logf(red[0]) + mx;
    if (tid < 250) out[(size_t)b * 250 + tid] = logit - lse;
}

// ===========================================================================
extern "C" void kernel_launch(void* const* d_in, const int* in_sizes, int n_in,
                              void* d_out, int out_size, void* d_ws, size_t ws_size,
                              hipStream_t stream)
{
    const float* s_in = (const float*)d_in[0];
    const float* c1w = (const float*)d_in[1];  const float* c1b = (const float*)d_in[2];
    const float* g1  = (const float*)d_in[3];  const float* b1  = (const float*)d_in[4];
    const float* c2w = (const float*)d_in[5];  const float* c2b = (const float*)d_in[6];
    const float* g2  = (const float*)d_in[7];  const float* b2  = (const float*)d_in[8];
    const float* c3w = (const float*)d_in[9];  const float* c3b = (const float*)d_in[10];
    const float* g3  = (const float*)d_in[11]; const float* b3  = (const float*)d_in[12];
    const float* c4w = (const float*)d_in[13]; const float* c4b = (const float*)d_in[14];
    const float* g4  = (const float*)d_in[15]; const float* b4  = (const float*)d_in[16];
    const float* ofw = (const float*)d_in[17]; const float* ofb = (const float*)d_in[18];
    const float* dcw = (const float*)d_in[19];
    const float* g5  = (const float*)d_in[20]; const float* b5  = (const float*)d_in[21];
    const float* fcw = (const float*)d_in[22]; const float* fcb = (const float*)d_in[23];

    float* ws   = (float*)d_ws;
    float* stat = ws;                       // 2560
    float* ab   = ws + 2560;                // 2560
    float* zpad = ws + 5120;                // 64
    ushort* w2  = (ushort*)(ws + 5184);     // 73728 u
    ushort* w3  = (ushort*)(ws + 78912);    // 294912 u
    ushort* w4  = (ushort*)(ws + 373824);   // 589824 u
    ushort* wd  = (ushort*)(ws + 963648);   // 589824 u
    ushort* pool16 = (ushort*)(ws + 1553472);  // 8,388,608 u max
    float*  conv32 = ws + 9942080;             // pooled conv2/conv3 outs (fp32)
    float*  c4parts = ws + 9942080;            // conv4 split-K parts (4 x 2,097,152)
    float*  c4out   = ws + 18330688;           // conv4 summed (2,097,152)
    float*  dparts  = ws + 20427840;           // dconv split-K parts (8 x 524,288)
    ushort* xo16 = (ushort*)(ws + 9942080);    // 4,718,592 u (after conv4 parts dead)
    float*  dout = ws + 14660672;              // 524,288 f
    float*  offb = ws + 15184960;              // 36,864 f

    hipMemsetAsync(stat, 0, 2048 * sizeof(float), stream);
    hipMemsetAsync(zpad, 0, 256, stream);

    // weight conversions (fp32 -> fp16, OHWI reorder for convs, direct for dconv)
    wcvt_kernel<<<(128 * 64 * 9 + 255) / 256, 256, 0, stream>>>(c2w, w2, 64, 1, 128 * 64 * 9);
    wcvt_kernel<<<(256 * 128 * 9 + 255) / 256, 256, 0, stream>>>(c3w, w3, 128, 1, 256 * 128 * 9);
    wcvt_kernel<<<(256 * 256 * 9 + 255) / 256, 256, 0, stream>>>(c4w, w4, 256, 1, 256 * 256 * 9);
    wcvt_kernel<<<(256 * 2304 + 255) / 256, 256, 0, stream>>>(dcw, wd, 256, 0, 256 * 2304);

    // ---- stage 1: conv1 (recompute trick) -> fp16 NHWC [B,32,32,64] ----
    conv1_kernel<1><<<dim3(512, 8), 256, 0, stream>>>(s_in, c1w, c1b, nullptr,
                                                      stat, stat + 256, nullptr, nullptr);
    bn_finalize<<<1, 256, 0, stream>>>(stat, stat + 256, g1, b1, ab, ab + 256, 64,
                                       1.0f / (128.f * 64.f * 64.f));
    conv1_kernel<2><<<dim3(512, 8), 256, 0, stream>>>(s_in, c1w, c1b, pool16,
                                                      nullptr, nullptr, ab, ab + 256);

    // ---- stage 2: conv2 GEMM (M=131072, N=128, K=576), fused pool ----
    gemm_kernel<576, 64, 32, 32, 128, true, true, true, 1, 128, true>
        <<<dim3(1024, 1), 256, 0, stream>>>(
        pool16, w2, c2b, conv32, (const ushort*)zpad, stat + 512, stat + 768);
    bn_finalize<<<1, 256, 0, stream>>>(stat + 512, stat + 768, g2, b2, ab + 512, ab + 768,
                                       128, 1.0f / (128.f * 32.f * 32.f));
    affine_split_kernel<128><<<2048, 256, 0, stream>>>(conv32, ab + 512, ab + 768, pool16);

    // ---- stage 3: conv3 GEMM (M=32768, N=256, K=1152), fused pool ----
    gemm_kernel<1152, 128, 16, 16, 256, true, true, true, 1, 128, true>
        <<<dim3(256, 2), 256, 0, stream>>>(
        pool16, w3, c3b, conv32, (const ushort*)zpad, stat + 1024, stat + 1280);
    bn_finalize<<<1, 256, 0, stream>>>(stat + 1024, stat + 1280, g3, b3, ab + 1024, ab + 1280,
                                       256, 1.0f / (128.f * 16.f * 16.f));
    affine_split_kernel<256><<<1024, 256, 0, stream>>>(conv32, ab + 1024, ab + 1280, pool16);

    // ---- stage 4: conv4 GEMM (M=8192, N=256, K=2304), split-K=4 ----
    gemm_kernel<2304, 256, 8, 8, 256, true, false, false, 4, 128, false>
        <<<dim3(64, 2, 4), 256, 0, stream>>>(
        pool16, w4, nullptr, c4parts, (const ushort*)zpad, nullptr, nullptr);
    sumk_kernel<4, true, true><<<1024, 256, 0, stream>>>(
        c4parts, 2097152, c4b, c4out, stat + 1536, stat + 1792);
    bn_finalize<<<1, 256, 0, stream>>>(stat + 1536, stat + 1792, g4, b4, ab + 1536, ab + 1792,
                                       256, 1.0f / (128.f * 8.f * 8.f));
    bnpool_kernel<256, 8, 8><<<256, 256, 0, stream>>>(c4out, ab + 1536, ab + 1792, pool16);

    // ---- deformable conv (split-K=8) ----
    offconv_kernel<<<dim3(128, 2), 256, 0, stream>>>(pool16, ofw, ofb, offb);
    sample_kernel<<<128, 256, 0, stream>>>(pool16, offb, xo16);
    gemm_kernel<2304, 2304, 1, 1, 256, false, false, false, 8, 64, false>
        <<<dim3(16, 4, 8), 256, 0, stream>>>(
        xo16, wd, nullptr, dparts, (const ushort*)zpad, nullptr, nullptr);
    sumk_kernel<8, false, false><<<256, 256, 0, stream>>>(
        dparts, 524288, nullptr, dout, nullptr, nullptr);

    // ---- bn5 + head ----
    stats5_kernel<<<256, 256, 0, stream>>>(dout, stat + 2048, stat + 2304);
    bn_finalize<<<1, 256, 0, stream>>>(stat + 2048, stat + 2304, g5, b5, ab + 2048, ab + 2304,
                                       256, 1.0f / 2048.f);
    final_kernel<<<128, 256, 0, stream>>>(dout, ab + 2048, ab + 2304, fcw, fcb, (float*)d_out);
}